// Round 2
// baseline (1018.995 us; speedup 1.0000x reference)
//
#include <hip/hip_runtime.h>
#include <math.h>

#define NN_   6000
#define EE_   192000
#define CIN_  32
#define CHID_ 64
#define KK_   125   // 5^3 spline kernel cells
#define EB_   32    // edge batch per block in build_T
#define CH1_  4     // x-GEMM outer chunks (each = CPB*64 cols)
#define CH2_  8     // h-GEMM outer chunks
#define CPB_  16    // k-chunks per GEMM block (64 cols each)

// fp32 -> bf16 round-to-nearest-even
static __device__ __forceinline__ unsigned short f2bf(float f) {
    unsigned int u = __builtin_bit_cast(unsigned int, f);
    u += 0x7fff + ((u >> 16) & 1);
    return (unsigned short)(u >> 16);
}
static __device__ __forceinline__ float bf2f(unsigned short h) {
    unsigned int u = ((unsigned int)h) << 16;
    return __builtin_bit_cast(float, u);
}

// 32-bit LDS byte offset of a __shared__ object (generic -> addrspace(3) cast).
static __device__ __forceinline__ unsigned lds_off(const void* p) {
    return (unsigned)(unsigned long long)
        (__attribute__((address_space(3))) const char*)p;
}

// ---------------------------------------------------------------------------
// Launch 1: deg count + weight packs (independent work, one launch).
// ---------------------------------------------------------------------------
#define PK1_ (192 * KK_ * CIN_)    // 768000
#define PK2_ (128 * KK_ * CHID_)   // 1024000
#define CB_  ((EE_ + 255) / 256)   // 750 count blocks
__global__ __launch_bounds__(256) void count_pack_kernel(
    const int* __restrict__ ei, int* __restrict__ deg,
    const float* __restrict__ W_xr, const float* __restrict__ W_xz,
    const float* __restrict__ W_xn, const float* __restrict__ W_hr,
    const float* __restrict__ W_hz,
    unsigned short* __restrict__ B1t, unsigned short* __restrict__ B2t)
{
    const int b = blockIdx.x;
    if (b < CB_) {
        int e = b * 256 + threadIdx.x;
        if (e < EE_) atomicAdd(&deg[ei[EE_ + e]], 1);
        return;
    }
    int gid = (b - CB_) * 256 + threadIdx.x;
    if (gid < PK1_) {
        int n  = gid / (KK_ * CIN_);
        int kk = gid % (KK_ * CIN_);
        int conv = n >> 6, o = n & 63;
        const float* W = (conv == 0) ? W_xr : ((conv == 1) ? W_xz : W_xn);
        B1t[gid] = f2bf(W[(size_t)kk * 64 + o]);
    } else if (gid < PK1_ + PK2_) {
        int g2 = gid - PK1_;
        int n  = g2 / (KK_ * CHID_);
        int kk = g2 % (KK_ * CHID_);
        int conv = n >> 6, o = n & 63;
        const float* W = (conv == 0) ? W_hr : W_hz;
        B2t[g2] = f2bf(W[(size_t)kk * 64 + o]);
    }
}

__global__ __launch_bounds__(1024) void scan_kernel(
    const int* __restrict__ deg, int* __restrict__ offs, int* __restrict__ cursor)
{
    __shared__ int part[1024];
    const int tid = threadIdx.x;
    const int CH = (NN_ + 1023) / 1024;   // 6
    const int base = tid * CH;
    int loc[CH];
    int s = 0;
#pragma unroll
    for (int i = 0; i < CH; ++i) {
        int v = (base + i < NN_) ? deg[base + i] : 0;
        loc[i] = s; s += v;
    }
    part[tid] = s;
    __syncthreads();
    for (int off = 1; off < 1024; off <<= 1) {
        int v = (tid >= off) ? part[tid - off] : 0;
        __syncthreads();
        part[tid] += v;
        __syncthreads();
    }
    const int pre = (tid > 0) ? part[tid - 1] : 0;
#pragma unroll
    for (int i = 0; i < CH; ++i) {
        if (base + i < NN_) {
            offs[base + i]   = pre + loc[i];
            cursor[base + i] = pre + loc[i];
        }
    }
    if (tid == 1023) offs[NN_] = part[1023];
}

// Compute per-edge spline meta ONCE, scattered to dst-sorted position.
__global__ __launch_bounds__(256) void prep_kernel(
    const int* __restrict__ ei, const float* __restrict__ attr,
    int* __restrict__ cursor, float4* __restrict__ meta_s, int* __restrict__ src_s)
{
    int e = blockIdx.x * 256 + threadIdx.x;
    if (e >= EE_) return;
    const int dst = ei[EE_ + e];
    const int p   = atomicAdd(&cursor[dst], 1);
    float f[3]; int i0[3];
#pragma unroll
    for (int d = 0; d < 3; ++d) {
        float u  = attr[e * 3 + d] * 4.0f;
        float fl = floorf(u);
        fl = fminf(fmaxf(fl, 0.0f), 3.0f);
        i0[d] = (int)fl;
        f[d]  = u - fl;
    }
    meta_s[p] = make_float4(f[0], f[1], f[2],
        __int_as_float(i0[0] * 25 + i0[1] * 5 + i0[2]));
    src_s[p] = ei[e];
}

// ---------------------------------------------------------------------------
// Per-node T build v5: phase 3 uses raw ds_add_f32 via inline asm.
// R1 lesson: atomicAdd(__shared__ float*) compiles to a ds_cmpst CAS LOOP
// (546us, VALUBusy 4.7%) -- NOT ds_add_f32. The asm form is the true
// no-return fire-and-forget instruction: no result dependency, so the
// serial per-edge LDS round-trip chain (v3's bottleneck) disappears.
// No "memory" clobber: compiler may batch s_basis/s_fb reads across the
// unrolled iterations (barriers still order the asm). Atomicity keeps the
// EPI=2 same-cell race fixed (absmax 0.0156).
// PAD = C+3 (odd stride, ≡3 mod 32): v3's C+2 put every cell at an even
// bank (>=4-way conflict on wave64); odd stride mixes parity -> ~2-way
// (free per m136).
// ---------------------------------------------------------------------------
template<int C>
__global__ __launch_bounds__(256) void build_T_kernel(
    const float4* __restrict__ meta_s, const int* __restrict__ src_s,
    const float* __restrict__ feat, const int* __restrict__ offs,
    unsigned short* __restrict__ Tb)
{
    constexpr int PAD   = C + 3;                 // odd stride (floats)
    constexpr int NPAIR = C / 2;
    constexpr int NP2   = NPAIR / 2;             // float4 units per row
    constexpr int EPI   = (C == 32) ? 2 : 1;     // edges per iteration
    constexpr int PPW   = (C == 32) ? 4 : 8;     // pairs owned per wave
    __shared__ float        Tl[KK_ * PAD];
    __shared__ int          s_base[EB_];         // pre-multiplied by PAD
    __shared__ float        s_basis[EB_ * 8];
    __shared__ int          s_src[EB_];
    __shared__ unsigned int s_fb[EB_ * NPAIR];   // packed bf16 pairs

    const int node = blockIdx.x;
    const int tid  = threadIdx.x;
    const int wave = tid >> 6;
    const int lane = tid & 63;

    for (int i = tid; i < KK_ * PAD; i += 256) Tl[i] = 0.f;

    const int j0 = offs[node], j1 = offs[node + 1];

    const int e2   = (EPI == 2) ? (lane >> 5) : 0;
    const int s_c  = (EPI == 2) ? ((lane >> 2) & 7) : (lane >> 3);
    const int pl   = (EPI == 2) ? (lane & 3) : (lane & 7);
    const int pidx = wave * PPW + pl;
    const int cb0 = s_c & 1, cb1 = (s_c >> 1) & 1, cb2 = (s_c >> 2) & 1;
    const int offc = cb0 * 25 + cb1 * 5 + cb2;
    const unsigned tl_base = lds_off(Tl) + 4u * (unsigned)(offc * PAD + 2 * pidx);

    __syncthreads();

    for (int jb = j0; jb < j1; jb += EB_) {
        const int m = min(EB_, j1 - jb);

        // phase 1: load edge records; precompute base*PAD + all 8 basis products
        if (tid < m) {
            const float4 mt = meta_s[jb + tid];
            s_src[tid]  = src_s[jb + tid];
            s_base[tid] = __float_as_int(mt.w) * PAD;
            const float f0 = mt.x, f1 = mt.y, f2 = mt.z;
            const float g0 = 1.f - f0, g1 = 1.f - f1, g2 = 1.f - f2;
            float4 blo = make_float4(g0 * g1 * g2, f0 * g1 * g2,
                                     g0 * f1 * g2, f0 * f1 * g2);
            float4 bhi = make_float4(g0 * g1 * f2, f0 * g1 * f2,
                                     g0 * f1 * f2, f0 * f1 * f2);
            *(float4*)&s_basis[tid * 8]     = blo;
            *(float4*)&s_basis[tid * 8 + 4] = bhi;
        }
        __syncthreads();

        // phase 2: gather feature rows -> packed bf16 in LDS (float4 wide)
        for (int u = tid; u < m * NP2; u += 256) {
            const int r = u / NP2, q = u % NP2;
            float4 v = *(const float4*)&feat[(size_t)s_src[r] * C + 4 * q];
            unsigned int lo = (unsigned int)f2bf(v.x) | ((unsigned int)f2bf(v.y) << 16);
            unsigned int hi = (unsigned int)f2bf(v.z) | ((unsigned int)f2bf(v.w) << 16);
            *(uint2*)&s_fb[r * NPAIR + 2 * q] = make_uint2(lo, hi);
        }
        __syncthreads();

        // phase 3: fire-and-forget LDS accumulate (true ds_add_f32, no rtn)
#pragma unroll 4
        for (int eb = 0; eb < m; eb += EPI) {
            const int e = eb + e2;
            if (EPI == 1 || e < m) {
                const float p    = s_basis[e * 8 + s_c];
                const unsigned int fp = s_fb[e * NPAIR + pidx];
                const float fx = bf2f((unsigned short)(fp & 0xffff));
                const float fy = bf2f((unsigned short)(fp >> 16));
                const unsigned off = tl_base + 4u * (unsigned)s_base[e];
                asm volatile("ds_add_f32 %0, %1\n\t"
                             "ds_add_f32 %0, %2 offset:4"
                             :: "v"(off), "v"(p * fx), "v"(p * fy));
            }
        }
        __syncthreads();
    }

    // all ds_add_f32 drained by the barrier at the end of the last batch
    unsigned int* To = (unsigned int*)(Tb + (size_t)node * (KK_ * C));
    for (int u = tid; u < KK_ * NPAIR; u += 256) {
        int k = u / NPAIR, pp = u % NPAIR;
        unsigned int lo = f2bf(Tl[k * PAD + 2 * pp]);
        unsigned int hi = f2bf(Tl[k * PAD + 2 * pp + 1]);
        To[u] = lo | (hi << 16);
    }
}

// ---------------------------------------------------------------------------
// GEMM body v7 (R21-proven): COLS=64, CPB=16, barrier-free inner loop,
// A-frags per-lane direct from global, no cross-chunk prefetch (R19 lesson).
// ---------------------------------------------------------------------------
template<int NT, int NTF, int CPB>
static __device__ __forceinline__ void gemm_body(
    unsigned char* arena,
    const unsigned short* __restrict__ A, const unsigned short* __restrict__ Bt,
    unsigned short* __restrict__ P, int M, int Kd, int chunk, int zhalf)
{
    constexpr int SPC   = 2;
    constexpr int COLS  = SPC * 32;       // 64
    constexpr int BP    = COLS + 8;       // 72 shorts
    constexpr int NFRAG = NT / 16;
    constexpr int CSP   = NT + 8;
    unsigned short (*Bs)[BP] = (unsigned short(*)[BP])arena;

    using bf16x8 = __attribute__((ext_vector_type(8))) short;
    using f32x4  = __attribute__((ext_vector_type(4))) float;

    const int tid  = threadIdx.x;
    const int wave = tid >> 6;
    const int lane = tid & 63;
    const int quad = lane >> 4;
    const int l16  = lane & 15;
    const int m0   = blockIdx.x * 64;
    const unsigned short* Bp = Bt + (size_t)zhalf * NT * Kd;

    const int  arow   = m0 + wave * 16 + l16;
    const bool avalid = arow < M;
    const unsigned short* Ap = A + (size_t)(avalid ? arow : 0) * Kd;

    f32x4 acc[NFRAG];
#pragma unroll
    for (int f = 0; f < NFRAG; ++f) acc[f] = (f32x4){0.f, 0.f, 0.f, 0.f};

    for (int cc = 0; cc < CPB; ++cc) {
        const int k0 = (chunk * CPB + cc) * COLS;
        if (k0 >= Kd) break;
        const int ksz = min(Kd - k0, COLS);

        __syncthreads();

        constexpr int BUNITS = NT * COLS / 8;
        for (int u = tid; u < BUNITS; u += 256) {
            const int row = u / (COLS / 8);
            const int cq  = (u % (COLS / 8)) * 8;
            uint4 v = make_uint4(0u, 0u, 0u, 0u);
            if (cq < ksz) v = *(const uint4*)(Bp + (size_t)row * Kd + k0 + cq);
            *(uint4*)&Bs[row][cq] = v;
        }

        uint4 afr[SPC];
#pragma unroll
        for (int s = 0; s < SPC; ++s) {
            const int k = k0 + s * 32 + quad * 8;
            afr[s] = (avalid && k < Kd) ? *(const uint4*)(Ap + k)
                                        : make_uint4(0u, 0u, 0u, 0u);
        }

        __syncthreads();

#pragma unroll
        for (int s = 0; s < SPC; ++s) {
            bf16x8 af = __builtin_bit_cast(bf16x8, afr[s]);
#pragma unroll
            for (int f = 0; f < NFRAG; ++f) {
                bf16x8 bfv = *(bf16x8*)&Bs[f * 16 + l16][s * 32 + quad * 8];
                acc[f] = __builtin_amdgcn_mfma_f32_16x16x32_bf16(af, bfv, acc[f], 0, 0, 0);
            }
        }
    }

    __syncthreads();
    unsigned short* Cs = (unsigned short*)arena;   // [64][CSP]
    const int rbase = wave * 16 + quad * 4;
#pragma unroll
    for (int f = 0; f < NFRAG; ++f) {
        const int col = f * 16 + l16;
#pragma unroll
        for (int r = 0; r < 4; ++r)
            Cs[(rbase + r) * CSP + col] = f2bf(acc[f][r]);
    }
    __syncthreads();
    unsigned short* Pc = P + ((size_t)chunk * M + m0) * NTF + zhalf * NT;
    constexpr int UNITS = 64 * NT / 8;
    for (int u = tid; u < UNITS; u += 256) {
        const int row = (u * 8) / NT, col = (u * 8) % NT;
        if (m0 + row < M)
            *(uint4*)&Pc[(size_t)row * NTF + col] = *(const uint4*)&Cs[row * CSP + col];
    }
}

// Merged GEMM: blockIdx.y < CH2_ -> h-chunk; else x-(chunk,half).
__global__ __launch_bounds__(256) void gemm_all_kernel(
    const unsigned short* __restrict__ Tx, const unsigned short* __restrict__ B1t,
    unsigned short* __restrict__ P1,
    const unsigned short* __restrict__ Th, const unsigned short* __restrict__ B2t,
    unsigned short* __restrict__ P2)
{
    __shared__ __align__(16) unsigned char arena[128 * 72 * 2];
    const int y = blockIdx.y;
    if (y < CH2_) {
        gemm_body<128, 128, CPB_>(arena, Th, B2t, P2, NN_, KK_ * CHID_, y, 0);
    } else {
        const int g = y - CH2_;            // 0..7 -> (chunk 0..3, half 0..1)
        gemm_body<96, 192, CPB_>(arena, Tx, B1t, P1, NN_, KK_ * CIN_, g >> 1, g & 1);
    }
}

// ---------------------------------------------------------------------------
// Epilogue: one wave per node, lane = output channel. Sums bf16 split-K
// partials (L2-resident), mean-agg, root GEMV, GRU gates.
// ---------------------------------------------------------------------------
__global__ __launch_bounds__(256) void epilogue_kernel(
    const unsigned short* __restrict__ P1, const unsigned short* __restrict__ P2,
    const int* __restrict__ offs,
    const float* __restrict__ x, const float* __restrict__ hidden,
    const float* __restrict__ root_xr, const float* __restrict__ root_hr,
    const float* __restrict__ root_xz, const float* __restrict__ root_hz,
    const float* __restrict__ root_xn,
    const float* __restrict__ b_xr, const float* __restrict__ b_hr,
    const float* __restrict__ b_xz, const float* __restrict__ b_hz,
    const float* __restrict__ b_xn,
    float* __restrict__ out)
{
    __shared__ float xsh[4][32];
    __shared__ float hsh[4][64];
    const int w = threadIdx.x >> 6;
    const int o = threadIdx.x & 63;
    const int m = blockIdx.x * 4 + w;
    if (m >= NN_) return;

    if (o < 32) xsh[w][o] = x[(size_t)m * 32 + o];
    const float hval = hidden[(size_t)m * 64 + o];
    hsh[w][o] = hval;

    float axr = 0.f, axz = 0.f, axn = 0.f;
#pragma unroll
    for (int c = 0; c < CH1_; ++c) {
        const unsigned short* p = P1 + ((size_t)c * NN_ + m) * 192;
        axr += bf2f(p[o]); axz += bf2f(p[64 + o]); axn += bf2f(p[128 + o]);
    }
    float ahr = 0.f, ahz = 0.f;
#pragma unroll
    for (int c = 0; c < CH2_; ++c) {
        const unsigned short* p = P2 + ((size_t)c * NN_ + m) * 128;
        ahr += bf2f(p[o]); ahz += bf2f(p[64 + o]);
    }

    const int   dg   = offs[m + 1] - offs[m];
    const float dinv = 1.0f / fmaxf((float)dg, 1.0f);
    axr *= dinv; axz *= dinv; axn *= dinv; ahr *= dinv; ahz *= dinv;

    float sxr = 0.f, sxz = 0.f, sxn = 0.f;
#pragma unroll
    for (int c = 0; c < CIN_; ++c) {
        float xv = xsh[w][c];
        sxr += xv * root_xr[c * 64 + o];
        sxz += xv * root_xz[c * 64 + o];
        sxn += xv * root_xn[c * 64 + o];
    }
    float shr = 0.f, shz = 0.f;
#pragma unroll
    for (int c = 0; c < CHID_; ++c) {
        float hv = hsh[w][c];
        shr += hv * root_hr[c * 64 + o];
        shz += hv * root_hz[c * 64 + o];
    }

    const float conv_xr = axr + sxr + b_xr[o];
    const float conv_xz = axz + sxz + b_xz[o];
    const float conv_xn = axn + sxn + b_xn[o];
    const float hr_out  = ahr + shr + b_hr[o];
    const float conv_hz = ahz + shz + b_hz[o];

    const float rg = 1.0f / (1.0f + expf(-(conv_xr + hr_out)));
    const float zg = 1.0f / (1.0f + expf(-(conv_xz + conv_hz)));
    const float ng = tanhf(conv_xn + rg * hr_out);
    out[(size_t)m * 64 + o] = (1.0f - zg) * ng + zg * hval;
}

// ---------------------------------------------------------------------------
extern "C" void kernel_launch(void* const* d_in, const int* in_sizes, int n_in,
                              void* d_out, int out_size, void* d_ws, size_t ws_size,
                              hipStream_t stream)
{
    const float* x       = (const float*)d_in[0];
    const float* hidden  = (const float*)d_in[1];
    const int*   ei      = (const int*)  d_in[2];
    const float* attr    = (const float*)d_in[3];
    const float* W_xr    = (const float*)d_in[4];
    const float* root_xr = (const float*)d_in[5];
    const float* b_xr    = (const float*)d_in[6];
    const float* W_hr    = (const float*)d_in[7];
    const float* root_hr = (const float*)d_in[8];
    const float* b_hr    = (const float*)d_in[9];
    const float* W_xz    = (const float*)d_in[10];
    const float* root_xz = (const float*)d_in[11];
    const float* b_xz    = (const float*)d_in[12];
    const float* W_hz    = (const float*)d_in[13];
    const float* root_hz = (const float*)d_in[14];
    const float* b_hz    = (const float*)d_in[15];
    const float* W_xn    = (const float*)d_in[16];
    const float* root_xn = (const float*)d_in[17];
    const float* b_xn    = (const float*)d_in[18];
    // d_in[19..21] (W_hn/root_hn/b_hn) are dead: reference reuses hr_out.
    float* out = (float*)d_out;

    // Workspace (~175 MB). No aliasing (gemm-x reads Tx while gemm-h writes
    // P2 concurrently inside gemm_all).
    char* w = (char*)d_ws;
    unsigned short* Tx  = (unsigned short*)w; w += (size_t)NN_ * KK_ * CIN_  * 2;  // 48 MB
    unsigned short* Th  = (unsigned short*)w; w += (size_t)NN_ * KK_ * CHID_ * 2;  // 96 MB
    unsigned short* B1t = (unsigned short*)w; w += (size_t)192 * KK_ * CIN_  * 2;  // 1.5 MB
    unsigned short* B2t = (unsigned short*)w; w += (size_t)128 * KK_ * CHID_ * 2;  // 2.0 MB
    unsigned short* P1  = (unsigned short*)w; w += (size_t)CH1_ * NN_ * 192 * 2;   // 9.2 MB
    unsigned short* P2  = (unsigned short*)w; w += (size_t)CH2_ * NN_ * 128 * 2;   // 12.3 MB
    float4* meta_s = (float4*)w; w += (size_t)EE_ * 16;                            // 3.07 MB
    int* src_s  = (int*)w;   w += (size_t)EE_ * 4;                                 // 0.77 MB
    int* deg    = (int*)w;   w += (size_t)NN_ * 4;
    int* offs   = (int*)w;   w += (size_t)(NN_ + 4) * 4;
    int* cursor = (int*)w;   w += (size_t)NN_ * 4;

    const int MT = (NN_ + 63) / 64;   // 94 m-tiles

    hipMemsetAsync(deg, 0, (size_t)NN_ * 4, stream);

    // ---- launch 1: deg count + weight packs (independent, merged) ----
    const int PACKB = (PK1_ + PK2_ + 255) / 256;
    count_pack_kernel<<<CB_ + PACKB, 256, 0, stream>>>(
        ei, deg, W_xr, W_xz, W_xn, W_hr, W_hz, B1t, B2t);

    // ---- scan + sorted edge records ----
    scan_kernel<<<1, 1024, 0, stream>>>(deg, offs, cursor);
    prep_kernel<<<(EE_ + 255) / 256, 256, 0, stream>>>(ei, attr, cursor, meta_s, src_s);

    // ---- T builds: separate kernels so LDS arena is per-C sized ----
    build_T_kernel<CHID_><<<NN_, 256, 0, stream>>>(meta_s, src_s, hidden, offs, Th);
    build_T_kernel<CIN_><<<NN_, 256, 0, stream>>>(meta_s, src_s, x, offs, Tx);

    // ---- merged x+h GEMMs (co-resident, one launch) ----
    gemm_all_kernel<<<dim3(MT, CH2_ + 2 * CH1_), 256, 0, stream>>>(
        Tx, B1t, P1, Th, B2t, P2);

    // ---- fused reduce + GRU epilogue (wave per node) ----
    epilogue_kernel<<<(NN_ + 3) / 4, 256, 0, stream>>>(
        P1, P2, offs, x, hidden,
        root_xr, root_hr, root_xz, root_hz, root_xn,
        b_xr, b_hr, b_xz, b_hz, b_xn, out);
}

// Round 3
// 251.830 us; speedup vs baseline: 4.0464x; 4.0464x over previous
//
#include <hip/hip_runtime.h>
#include <math.h>

#define NN_   6000
#define EE_   192000
#define CIN_  32
#define CHID_ 64
#define KK_   125   // 5^3 spline kernel cells
#define EB_   32    // edge batch per block in build_T (= MFMA K)
#define CH1_  4     // x-GEMM outer chunks (each = CPB*64 cols)
#define CH2_  8     // h-GEMM outer chunks
#define CPB_  16    // k-chunks per GEMM block (64 cols each)

// fp32 -> bf16 round-to-nearest-even
static __device__ __forceinline__ unsigned short f2bf(float f) {
    unsigned int u = __builtin_bit_cast(unsigned int, f);
    u += 0x7fff + ((u >> 16) & 1);
    return (unsigned short)(u >> 16);
}
static __device__ __forceinline__ float bf2f(unsigned short h) {
    unsigned int u = ((unsigned int)h) << 16;
    return __builtin_bit_cast(float, u);
}

// ---------------------------------------------------------------------------
// Launch 1: deg count + weight packs (independent work, one launch).
// ---------------------------------------------------------------------------
#define PK1_ (192 * KK_ * CIN_)    // 768000
#define PK2_ (128 * KK_ * CHID_)   // 1024000
#define CB_  ((EE_ + 255) / 256)   // 750 count blocks
__global__ __launch_bounds__(256) void count_pack_kernel(
    const int* __restrict__ ei, int* __restrict__ deg,
    const float* __restrict__ W_xr, const float* __restrict__ W_xz,
    const float* __restrict__ W_xn, const float* __restrict__ W_hr,
    const float* __restrict__ W_hz,
    unsigned short* __restrict__ B1t, unsigned short* __restrict__ B2t)
{
    const int b = blockIdx.x;
    if (b < CB_) {
        int e = b * 256 + threadIdx.x;
        if (e < EE_) atomicAdd(&deg[ei[EE_ + e]], 1);
        return;
    }
    int gid = (b - CB_) * 256 + threadIdx.x;
    if (gid < PK1_) {
        int n  = gid / (KK_ * CIN_);
        int kk = gid % (KK_ * CIN_);
        int conv = n >> 6, o = n & 63;
        const float* W = (conv == 0) ? W_xr : ((conv == 1) ? W_xz : W_xn);
        B1t[gid] = f2bf(W[(size_t)kk * 64 + o]);
    } else if (gid < PK1_ + PK2_) {
        int g2 = gid - PK1_;
        int n  = g2 / (KK_ * CHID_);
        int kk = g2 % (KK_ * CHID_);
        int conv = n >> 6, o = n & 63;
        const float* W = (conv == 0) ? W_hr : W_hz;
        B2t[g2] = f2bf(W[(size_t)kk * 64 + o]);
    }
}

__global__ __launch_bounds__(1024) void scan_kernel(
    const int* __restrict__ deg, int* __restrict__ offs, int* __restrict__ cursor)
{
    __shared__ int part[1024];
    const int tid = threadIdx.x;
    const int CH = (NN_ + 1023) / 1024;   // 6
    const int base = tid * CH;
    int loc[CH];
    int s = 0;
#pragma unroll
    for (int i = 0; i < CH; ++i) {
        int v = (base + i < NN_) ? deg[base + i] : 0;
        loc[i] = s; s += v;
    }
    part[tid] = s;
    __syncthreads();
    for (int off = 1; off < 1024; off <<= 1) {
        int v = (tid >= off) ? part[tid - off] : 0;
        __syncthreads();
        part[tid] += v;
        __syncthreads();
    }
    const int pre = (tid > 0) ? part[tid - 1] : 0;
#pragma unroll
    for (int i = 0; i < CH; ++i) {
        if (base + i < NN_) {
            offs[base + i]   = pre + loc[i];
            cursor[base + i] = pre + loc[i];
        }
    }
    if (tid == 1023) offs[NN_] = part[1023];
}

// Compute per-edge spline meta ONCE, scattered to dst-sorted position.
__global__ __launch_bounds__(256) void prep_kernel(
    const int* __restrict__ ei, const float* __restrict__ attr,
    int* __restrict__ cursor, float4* __restrict__ meta_s, int* __restrict__ src_s)
{
    int e = blockIdx.x * 256 + threadIdx.x;
    if (e >= EE_) return;
    const int dst = ei[EE_ + e];
    const int p   = atomicAdd(&cursor[dst], 1);
    float f[3]; int i0[3];
#pragma unroll
    for (int d = 0; d < 3; ++d) {
        float u  = attr[e * 3 + d] * 4.0f;
        float fl = floorf(u);
        fl = fminf(fmaxf(fl, 0.0f), 3.0f);
        i0[d] = (int)fl;
        f[d]  = u - fl;
    }
    meta_s[p] = make_float4(f[0], f[1], f[2],
        __int_as_float(i0[0] * 25 + i0[1] * 5 + i0[2]));
    src_s[p] = ei[e];
}

// ---------------------------------------------------------------------------
// Per-node T build v6: dense-MFMA reformulation.
//   T[k][c] += sum_e M[k][e] * feat[e][c],  M[k][e] = basis_s(e) at k=cell(e,s)
// Per 32-edge batch = one K=32 MFMA step. M build is RACE-FREE scatter
// (thread-per-edge owns its column; the 8 cells per edge are distinct rows)
// with plain ds_write_b16 -- no RMW chain, no atomics (R1/R2 lesson: LDS
// atomics serialize on lgkmcnt; manual RMW serializes on the dep chain).
// Accumulators live in registers across batches; T written once at the end.
// Fragment layouts copied from the proven gemm_body (A row=l16,k=quad*8;
// B col=l16,k=quad*8; D col=lane&15,row=quad*4+reg).
// ---------------------------------------------------------------------------
template<int C>
__global__ __launch_bounds__(256) void build_T_kernel(
    const float4* __restrict__ meta_s, const int* __restrict__ src_s,
    const float* __restrict__ feat, const int* __restrict__ offs,
    unsigned short* __restrict__ Tb)
{
    constexpr int MP  = 40;              // padded row stride (shorts): 80B, odd word count
    constexpr int CT  = C / 16;          // B col-tiles (4 or 2)
    constexpr int CPT = C / 8;           // channels per fbT-fill thread (8 thr/edge)
    using bf16x8 = __attribute__((ext_vector_type(8))) short;
    using f32x4  = __attribute__((ext_vector_type(4))) float;

    __shared__ __align__(16) unsigned short Mt [128 * MP];  // [cell 0..127][edge] bf16
    __shared__ __align__(16) unsigned short fbT[C   * MP];  // [channel][edge]    bf16
    __shared__ int s_src[EB_];

    const int tid  = threadIdx.x;
    const int wave = tid >> 6;
    const int lane = tid & 63;
    const int quad = lane >> 4;
    const int l16  = lane & 15;
    const int node = blockIdx.x;

    // zero fbT once: stale-garbage LDS may be NaN-patterned; NaN*0 = NaN in MFMA
    for (int i = tid; i < C * MP / 8; i += 256)
        ((uint4*)fbT)[i] = make_uint4(0u, 0u, 0u, 0u);

    const int j0 = offs[node], j1 = offs[node + 1];

    f32x4 acc[2][CT];
#pragma unroll
    for (int t = 0; t < 2; ++t)
#pragma unroll
        for (int ct = 0; ct < CT; ++ct) acc[t][ct] = (f32x4){0.f, 0.f, 0.f, 0.f};

    for (int jb = j0; jb < j1; jb += EB_) {
        const int m = min(EB_, j1 - jb);

        __syncthreads();   // prev batch MFMA reads (and initial fbT zero) done
        // re-zero M so stale cells / partial-batch columns contribute exactly 0
        for (int i = tid; i < 128 * MP / 8; i += 256)
            ((uint4*)Mt)[i] = make_uint4(0u, 0u, 0u, 0u);
        if (tid < m) s_src[tid] = src_s[jb + tid];
        __syncthreads();

        // build M: thread-per-edge, 8 distinct rows of own column (race-free)
        if (tid < m) {
            const float4 mt = meta_s[jb + tid];
            const int base = __float_as_int(mt.w);
            const float f0 = mt.x, f1 = mt.y, f2 = mt.z;
            const float g0 = 1.f - f0, g1 = 1.f - f1, g2 = 1.f - f2;
            const float bb[8] = {g0*g1*g2, f0*g1*g2, g0*f1*g2, f0*f1*g2,
                                 g0*g1*f2, f0*g1*f2, g0*f1*f2, f0*f1*f2};
            const int oc[8] = {0, 25, 5, 30, 1, 26, 6, 31};
#pragma unroll
            for (int s = 0; s < 8; ++s)
                Mt[(base + oc[s]) * MP + tid] = f2bf(bb[s]);
        }
        // build B = feat^T: 8 threads per edge, CPT channels each
        {
            const int e = tid >> 3, cg = (tid & 7) * CPT;
            if (e < m) {
                const float* fr = &feat[(size_t)s_src[e] * C + cg];
#pragma unroll
                for (int c4 = 0; c4 < CPT; c4 += 4) {
                    float4 v = *(const float4*)(fr + c4);
                    fbT[(cg + c4 + 0) * MP + e] = f2bf(v.x);
                    fbT[(cg + c4 + 1) * MP + e] = f2bf(v.y);
                    fbT[(cg + c4 + 2) * MP + e] = f2bf(v.z);
                    fbT[(cg + c4 + 3) * MP + e] = f2bf(v.w);
                }
            }
        }
        __syncthreads();

        // MFMA: wave owns row-tiles wave*2+{0,1}; one K=32 step per batch
        bf16x8 a0 = *(const bf16x8*)&Mt[((wave * 2 + 0) * 16 + l16) * MP + quad * 8];
        bf16x8 a1 = *(const bf16x8*)&Mt[((wave * 2 + 1) * 16 + l16) * MP + quad * 8];
#pragma unroll
        for (int ct = 0; ct < CT; ++ct) {
            bf16x8 b = *(const bf16x8*)&fbT[(ct * 16 + l16) * MP + quad * 8];
            acc[0][ct] = __builtin_amdgcn_mfma_f32_16x16x32_bf16(a0, b, acc[0][ct], 0, 0, 0);
            acc[1][ct] = __builtin_amdgcn_mfma_f32_16x16x32_bf16(a1, b, acc[1][ct], 0, 0, 0);
        }
    }

    // write T[node][cell][c] (cells 0..124) bf16, direct from accumulators
    unsigned short* To = Tb + (size_t)node * (KK_ * C);
#pragma unroll
    for (int t = 0; t < 2; ++t) {
        const int rbase = (wave * 2 + t) * 16 + quad * 4;
#pragma unroll
        for (int ct = 0; ct < CT; ++ct) {
#pragma unroll
            for (int r = 0; r < 4; ++r) {
                const int R = rbase + r;
                if (R < KK_) To[R * C + ct * 16 + l16] = f2bf(acc[t][ct][r]);
            }
        }
    }
}

// ---------------------------------------------------------------------------
// GEMM body v7 (R21-proven): COLS=64, CPB=16, barrier-free inner loop,
// A-frags per-lane direct from global, no cross-chunk prefetch (R19 lesson).
// ---------------------------------------------------------------------------
template<int NT, int NTF, int CPB>
static __device__ __forceinline__ void gemm_body(
    unsigned char* arena,
    const unsigned short* __restrict__ A, const unsigned short* __restrict__ Bt,
    unsigned short* __restrict__ P, int M, int Kd, int chunk, int zhalf)
{
    constexpr int SPC   = 2;
    constexpr int COLS  = SPC * 32;       // 64
    constexpr int BP    = COLS + 8;       // 72 shorts
    constexpr int NFRAG = NT / 16;
    constexpr int CSP   = NT + 8;
    unsigned short (*Bs)[BP] = (unsigned short(*)[BP])arena;

    using bf16x8 = __attribute__((ext_vector_type(8))) short;
    using f32x4  = __attribute__((ext_vector_type(4))) float;

    const int tid  = threadIdx.x;
    const int wave = tid >> 6;
    const int lane = tid & 63;
    const int quad = lane >> 4;
    const int l16  = lane & 15;
    const int m0   = blockIdx.x * 64;
    const unsigned short* Bp = Bt + (size_t)zhalf * NT * Kd;

    const int  arow   = m0 + wave * 16 + l16;
    const bool avalid = arow < M;
    const unsigned short* Ap = A + (size_t)(avalid ? arow : 0) * Kd;

    f32x4 acc[NFRAG];
#pragma unroll
    for (int f = 0; f < NFRAG; ++f) acc[f] = (f32x4){0.f, 0.f, 0.f, 0.f};

    for (int cc = 0; cc < CPB; ++cc) {
        const int k0 = (chunk * CPB + cc) * COLS;
        if (k0 >= Kd) break;
        const int ksz = min(Kd - k0, COLS);

        __syncthreads();

        constexpr int BUNITS = NT * COLS / 8;
        for (int u = tid; u < BUNITS; u += 256) {
            const int row = u / (COLS / 8);
            const int cq  = (u % (COLS / 8)) * 8;
            uint4 v = make_uint4(0u, 0u, 0u, 0u);
            if (cq < ksz) v = *(const uint4*)(Bp + (size_t)row * Kd + k0 + cq);
            *(uint4*)&Bs[row][cq] = v;
        }

        uint4 afr[SPC];
#pragma unroll
        for (int s = 0; s < SPC; ++s) {
            const int k = k0 + s * 32 + quad * 8;
            afr[s] = (avalid && k < Kd) ? *(const uint4*)(Ap + k)
                                        : make_uint4(0u, 0u, 0u, 0u);
        }

        __syncthreads();

#pragma unroll
        for (int s = 0; s < SPC; ++s) {
            bf16x8 af = __builtin_bit_cast(bf16x8, afr[s]);
#pragma unroll
            for (int f = 0; f < NFRAG; ++f) {
                bf16x8 bfv = *(bf16x8*)&Bs[f * 16 + l16][s * 32 + quad * 8];
                acc[f] = __builtin_amdgcn_mfma_f32_16x16x32_bf16(af, bfv, acc[f], 0, 0, 0);
            }
        }
    }

    __syncthreads();
    unsigned short* Cs = (unsigned short*)arena;   // [64][CSP]
    const int rbase = wave * 16 + quad * 4;
#pragma unroll
    for (int f = 0; f < NFRAG; ++f) {
        const int col = f * 16 + l16;
#pragma unroll
        for (int r = 0; r < 4; ++r)
            Cs[(rbase + r) * CSP + col] = f2bf(acc[f][r]);
    }
    __syncthreads();
    unsigned short* Pc = P + ((size_t)chunk * M + m0) * NTF + zhalf * NT;
    constexpr int UNITS = 64 * NT / 8;
    for (int u = tid; u < UNITS; u += 256) {
        const int row = (u * 8) / NT, col = (u * 8) % NT;
        if (m0 + row < M)
            *(uint4*)&Pc[(size_t)row * NTF + col] = *(const uint4*)&Cs[row * CSP + col];
    }
}

// Merged GEMM: blockIdx.y < CH2_ -> h-chunk; else x-(chunk,half).
__global__ __launch_bounds__(256) void gemm_all_kernel(
    const unsigned short* __restrict__ Tx, const unsigned short* __restrict__ B1t,
    unsigned short* __restrict__ P1,
    const unsigned short* __restrict__ Th, const unsigned short* __restrict__ B2t,
    unsigned short* __restrict__ P2)
{
    __shared__ __align__(16) unsigned char arena[128 * 72 * 2];
    const int y = blockIdx.y;
    if (y < CH2_) {
        gemm_body<128, 128, CPB_>(arena, Th, B2t, P2, NN_, KK_ * CHID_, y, 0);
    } else {
        const int g = y - CH2_;            // 0..7 -> (chunk 0..3, half 0..1)
        gemm_body<96, 192, CPB_>(arena, Tx, B1t, P1, NN_, KK_ * CIN_, g >> 1, g & 1);
    }
}

// ---------------------------------------------------------------------------
// Epilogue: one wave per node, lane = output channel. Sums bf16 split-K
// partials (L2-resident), mean-agg, root GEMV, GRU gates.
// ---------------------------------------------------------------------------
__global__ __launch_bounds__(256) void epilogue_kernel(
    const unsigned short* __restrict__ P1, const unsigned short* __restrict__ P2,
    const int* __restrict__ offs,
    const float* __restrict__ x, const float* __restrict__ hidden,
    const float* __restrict__ root_xr, const float* __restrict__ root_hr,
    const float* __restrict__ root_xz, const float* __restrict__ root_hz,
    const float* __restrict__ root_xn,
    const float* __restrict__ b_xr, const float* __restrict__ b_hr,
    const float* __restrict__ b_xz, const float* __restrict__ b_hz,
    const float* __restrict__ b_xn,
    float* __restrict__ out)
{
    __shared__ float xsh[4][32];
    __shared__ float hsh[4][64];
    const int w = threadIdx.x >> 6;
    const int o = threadIdx.x & 63;
    const int m = blockIdx.x * 4 + w;
    if (m >= NN_) return;

    if (o < 32) xsh[w][o] = x[(size_t)m * 32 + o];
    const float hval = hidden[(size_t)m * 64 + o];
    hsh[w][o] = hval;

    float axr = 0.f, axz = 0.f, axn = 0.f;
#pragma unroll
    for (int c = 0; c < CH1_; ++c) {
        const unsigned short* p = P1 + ((size_t)c * NN_ + m) * 192;
        axr += bf2f(p[o]); axz += bf2f(p[64 + o]); axn += bf2f(p[128 + o]);
    }
    float ahr = 0.f, ahz = 0.f;
#pragma unroll
    for (int c = 0; c < CH2_; ++c) {
        const unsigned short* p = P2 + ((size_t)c * NN_ + m) * 128;
        ahr += bf2f(p[o]); ahz += bf2f(p[64 + o]);
    }

    const int   dg   = offs[m + 1] - offs[m];
    const float dinv = 1.0f / fmaxf((float)dg, 1.0f);
    axr *= dinv; axz *= dinv; axn *= dinv; ahr *= dinv; ahz *= dinv;

    float sxr = 0.f, sxz = 0.f, sxn = 0.f;
#pragma unroll
    for (int c = 0; c < CIN_; ++c) {
        float xv = xsh[w][c];
        sxr += xv * root_xr[c * 64 + o];
        sxz += xv * root_xz[c * 64 + o];
        sxn += xv * root_xn[c * 64 + o];
    }
    float shr = 0.f, shz = 0.f;
#pragma unroll
    for (int c = 0; c < CHID_; ++c) {
        float hv = hsh[w][c];
        shr += hv * root_hr[c * 64 + o];
        shz += hv * root_hz[c * 64 + o];
    }

    const float conv_xr = axr + sxr + b_xr[o];
    const float conv_xz = axz + sxz + b_xz[o];
    const float conv_xn = axn + sxn + b_xn[o];
    const float hr_out  = ahr + shr + b_hr[o];
    const float conv_hz = ahz + shz + b_hz[o];

    const float rg = 1.0f / (1.0f + expf(-(conv_xr + hr_out)));
    const float zg = 1.0f / (1.0f + expf(-(conv_xz + conv_hz)));
    const float ng = tanhf(conv_xn + rg * hr_out);
    out[(size_t)m * 64 + o] = (1.0f - zg) * ng + zg * hval;
}

// ---------------------------------------------------------------------------
extern "C" void kernel_launch(void* const* d_in, const int* in_sizes, int n_in,
                              void* d_out, int out_size, void* d_ws, size_t ws_size,
                              hipStream_t stream)
{
    const float* x       = (const float*)d_in[0];
    const float* hidden  = (const float*)d_in[1];
    const int*   ei      = (const int*)  d_in[2];
    const float* attr    = (const float*)d_in[3];
    const float* W_xr    = (const float*)d_in[4];
    const float* root_xr = (const float*)d_in[5];
    const float* b_xr    = (const float*)d_in[6];
    const float* W_hr    = (const float*)d_in[7];
    const float* root_hr = (const float*)d_in[8];
    const float* b_hr    = (const float*)d_in[9];
    const float* W_xz    = (const float*)d_in[10];
    const float* root_xz = (const float*)d_in[11];
    const float* b_xz    = (const float*)d_in[12];
    const float* W_hz    = (const float*)d_in[13];
    const float* root_hz = (const float*)d_in[14];
    const float* b_hz    = (const float*)d_in[15];
    const float* W_xn    = (const float*)d_in[16];
    const float* root_xn = (const float*)d_in[17];
    const float* b_xn    = (const float*)d_in[18];
    // d_in[19..21] (W_hn/root_hn/b_hn) are dead: reference reuses hr_out.
    float* out = (float*)d_out;

    // Workspace (~175 MB). No aliasing (gemm-x reads Tx while gemm-h writes
    // P2 concurrently inside gemm_all).
    char* w = (char*)d_ws;
    unsigned short* Tx  = (unsigned short*)w; w += (size_t)NN_ * KK_ * CIN_  * 2;  // 48 MB
    unsigned short* Th  = (unsigned short*)w; w += (size_t)NN_ * KK_ * CHID_ * 2;  // 96 MB
    unsigned short* B1t = (unsigned short*)w; w += (size_t)192 * KK_ * CIN_  * 2;  // 1.5 MB
    unsigned short* B2t = (unsigned short*)w; w += (size_t)128 * KK_ * CHID_ * 2;  // 2.0 MB
    unsigned short* P1  = (unsigned short*)w; w += (size_t)CH1_ * NN_ * 192 * 2;   // 9.2 MB
    unsigned short* P2  = (unsigned short*)w; w += (size_t)CH2_ * NN_ * 128 * 2;   // 12.3 MB
    float4* meta_s = (float4*)w; w += (size_t)EE_ * 16;                            // 3.07 MB
    int* src_s  = (int*)w;   w += (size_t)EE_ * 4;                                 // 0.77 MB
    int* deg    = (int*)w;   w += (size_t)NN_ * 4;
    int* offs   = (int*)w;   w += (size_t)(NN_ + 4) * 4;
    int* cursor = (int*)w;   w += (size_t)NN_ * 4;

    const int MT = (NN_ + 63) / 64;   // 94 m-tiles

    hipMemsetAsync(deg, 0, (size_t)NN_ * 4, stream);

    // ---- launch 1: deg count + weight packs (independent, merged) ----
    const int PACKB = (PK1_ + PK2_ + 255) / 256;
    count_pack_kernel<<<CB_ + PACKB, 256, 0, stream>>>(
        ei, deg, W_xr, W_xz, W_xn, W_hr, W_hz, B1t, B2t);

    // ---- scan + sorted edge records ----
    scan_kernel<<<1, 1024, 0, stream>>>(deg, offs, cursor);
    prep_kernel<<<(EE_ + 255) / 256, 256, 0, stream>>>(ei, attr, cursor, meta_s, src_s);

    // ---- T builds: MFMA formulation ----
    build_T_kernel<CHID_><<<NN_, 256, 0, stream>>>(meta_s, src_s, hidden, offs, Th);
    build_T_kernel<CIN_><<<NN_, 256, 0, stream>>>(meta_s, src_s, x, offs, Tx);

    // ---- merged x+h GEMMs (co-resident, one launch) ----
    gemm_all_kernel<<<dim3(MT, CH2_ + 2 * CH1_), 256, 0, stream>>>(
        Tx, B1t, P1, Th, B2t, P2);

    // ---- fused reduce + GRU epilogue (wave per node) ----
    epilogue_kernel<<<(NN_ + 3) / 4, 256, 0, stream>>>(
        P1, P2, offs, x, hidden,
        root_xr, root_hr, root_xz, root_hz, root_xn,
        b_xr, b_hr, b_xz, b_hz, b_xn, out);
}

// Round 4
// 250.234 us; speedup vs baseline: 4.0722x; 1.0064x over previous
//
#include <hip/hip_runtime.h>
#include <math.h>

#define NN_   6000
#define EE_   192000
#define CIN_  32
#define CHID_ 64
#define KK_   125   // 5^3 spline kernel cells
#define EB_   32    // edge batch per block in build_T (= MFMA K)
#define CH1_  4     // x-GEMM outer chunks (each = CPB*64 cols)
#define CH2_  8     // h-GEMM outer chunks
#define CPB_  16    // k-chunks per GEMM block (64 cols each)
#define MTILE_ 192  // GEMM m-tile (4 waves x 3 row-frags x 16)

// fp32 -> bf16 round-to-nearest-even
static __device__ __forceinline__ unsigned short f2bf(float f) {
    unsigned int u = __builtin_bit_cast(unsigned int, f);
    u += 0x7fff + ((u >> 16) & 1);
    return (unsigned short)(u >> 16);
}
static __device__ __forceinline__ float bf2f(unsigned short h) {
    unsigned int u = ((unsigned int)h) << 16;
    return __builtin_bit_cast(float, u);
}

// ---------------------------------------------------------------------------
// Launch 1: deg count + weight packs (independent work, one launch).
// ---------------------------------------------------------------------------
#define PK1_ (192 * KK_ * CIN_)    // 768000
#define PK2_ (128 * KK_ * CHID_)   // 1024000
#define CB_  ((EE_ + 255) / 256)   // 750 count blocks
__global__ __launch_bounds__(256) void count_pack_kernel(
    const int* __restrict__ ei, int* __restrict__ deg,
    const float* __restrict__ W_xr, const float* __restrict__ W_xz,
    const float* __restrict__ W_xn, const float* __restrict__ W_hr,
    const float* __restrict__ W_hz,
    unsigned short* __restrict__ B1t, unsigned short* __restrict__ B2t)
{
    const int b = blockIdx.x;
    if (b < CB_) {
        int e = b * 256 + threadIdx.x;
        if (e < EE_) atomicAdd(&deg[ei[EE_ + e]], 1);
        return;
    }
    int gid = (b - CB_) * 256 + threadIdx.x;
    if (gid < PK1_) {
        int n  = gid / (KK_ * CIN_);
        int kk = gid % (KK_ * CIN_);
        int conv = n >> 6, o = n & 63;
        const float* W = (conv == 0) ? W_xr : ((conv == 1) ? W_xz : W_xn);
        B1t[gid] = f2bf(W[(size_t)kk * 64 + o]);
    } else if (gid < PK1_ + PK2_) {
        int g2 = gid - PK1_;
        int n  = g2 / (KK_ * CHID_);
        int kk = g2 % (KK_ * CHID_);
        int conv = n >> 6, o = n & 63;
        const float* W = (conv == 0) ? W_hr : W_hz;
        B2t[g2] = f2bf(W[(size_t)kk * 64 + o]);
    }
}

__global__ __launch_bounds__(1024) void scan_kernel(
    const int* __restrict__ deg, int* __restrict__ offs, int* __restrict__ cursor)
{
    __shared__ int part[1024];
    const int tid = threadIdx.x;
    const int CH = (NN_ + 1023) / 1024;   // 6
    const int base = tid * CH;
    int loc[CH];
    int s = 0;
#pragma unroll
    for (int i = 0; i < CH; ++i) {
        int v = (base + i < NN_) ? deg[base + i] : 0;
        loc[i] = s; s += v;
    }
    part[tid] = s;
    __syncthreads();
    for (int off = 1; off < 1024; off <<= 1) {
        int v = (tid >= off) ? part[tid - off] : 0;
        __syncthreads();
        part[tid] += v;
        __syncthreads();
    }
    const int pre = (tid > 0) ? part[tid - 1] : 0;
#pragma unroll
    for (int i = 0; i < CH; ++i) {
        if (base + i < NN_) {
            offs[base + i]   = pre + loc[i];
            cursor[base + i] = pre + loc[i];
        }
    }
    if (tid == 1023) offs[NN_] = part[1023];
}

// Compute per-edge spline meta ONCE, scattered to dst-sorted position.
__global__ __launch_bounds__(256) void prep_kernel(
    const int* __restrict__ ei, const float* __restrict__ attr,
    int* __restrict__ cursor, float4* __restrict__ meta_s, int* __restrict__ src_s)
{
    int e = blockIdx.x * 256 + threadIdx.x;
    if (e >= EE_) return;
    const int dst = ei[EE_ + e];
    const int p   = atomicAdd(&cursor[dst], 1);
    float f[3]; int i0[3];
#pragma unroll
    for (int d = 0; d < 3; ++d) {
        float u  = attr[e * 3 + d] * 4.0f;
        float fl = floorf(u);
        fl = fminf(fmaxf(fl, 0.0f), 3.0f);
        i0[d] = (int)fl;
        f[d]  = u - fl;
    }
    meta_s[p] = make_float4(f[0], f[1], f[2],
        __int_as_float(i0[0] * 25 + i0[1] * 5 + i0[2]));
    src_s[p] = ei[e];
}

// ---------------------------------------------------------------------------
// Per-node T build v6 (R3-proven): dense-MFMA reformulation.
// ---------------------------------------------------------------------------
template<int C>
__global__ __launch_bounds__(256) void build_T_kernel(
    const float4* __restrict__ meta_s, const int* __restrict__ src_s,
    const float* __restrict__ feat, const int* __restrict__ offs,
    unsigned short* __restrict__ Tb)
{
    constexpr int MP  = 40;              // padded row stride (shorts)
    constexpr int CT  = C / 16;          // B col-tiles (4 or 2)
    constexpr int CPT = C / 8;           // channels per fbT-fill thread
    using bf16x8 = __attribute__((ext_vector_type(8))) short;
    using f32x4  = __attribute__((ext_vector_type(4))) float;

    __shared__ __align__(16) unsigned short Mt [128 * MP];  // [cell][edge] bf16
    __shared__ __align__(16) unsigned short fbT[C   * MP];  // [channel][edge] bf16
    __shared__ int s_src[EB_];

    const int tid  = threadIdx.x;
    const int wave = tid >> 6;
    const int lane = tid & 63;
    const int quad = lane >> 4;
    const int l16  = lane & 15;
    const int node = blockIdx.x;

    // zero fbT once: stale LDS may be NaN-patterned; NaN*0 = NaN in MFMA
    for (int i = tid; i < C * MP / 8; i += 256)
        ((uint4*)fbT)[i] = make_uint4(0u, 0u, 0u, 0u);

    const int j0 = offs[node], j1 = offs[node + 1];

    f32x4 acc[2][CT];
#pragma unroll
    for (int t = 0; t < 2; ++t)
#pragma unroll
        for (int ct = 0; ct < CT; ++ct) acc[t][ct] = (f32x4){0.f, 0.f, 0.f, 0.f};

    for (int jb = j0; jb < j1; jb += EB_) {
        const int m = min(EB_, j1 - jb);

        __syncthreads();   // prev batch MFMA reads done
        for (int i = tid; i < 128 * MP / 8; i += 256)
            ((uint4*)Mt)[i] = make_uint4(0u, 0u, 0u, 0u);
        if (tid < m) s_src[tid] = src_s[jb + tid];
        __syncthreads();

        // build M: thread-per-edge, 8 distinct rows of own column (race-free)
        if (tid < m) {
            const float4 mt = meta_s[jb + tid];
            const int base = __float_as_int(mt.w);
            const float f0 = mt.x, f1 = mt.y, f2 = mt.z;
            const float g0 = 1.f - f0, g1 = 1.f - f1, g2 = 1.f - f2;
            const float bb[8] = {g0*g1*g2, f0*g1*g2, g0*f1*g2, f0*f1*g2,
                                 g0*g1*f2, f0*g1*f2, g0*f1*f2, f0*f1*f2};
            const int oc[8] = {0, 25, 5, 30, 1, 26, 6, 31};
#pragma unroll
            for (int s = 0; s < 8; ++s)
                Mt[(base + oc[s]) * MP + tid] = f2bf(bb[s]);
        }
        // build B = feat^T: 8 threads per edge, CPT channels each
        {
            const int e = tid >> 3, cg = (tid & 7) * CPT;
            if (e < m) {
                const float* fr = &feat[(size_t)s_src[e] * C + cg];
#pragma unroll
                for (int c4 = 0; c4 < CPT; c4 += 4) {
                    float4 v = *(const float4*)(fr + c4);
                    fbT[(cg + c4 + 0) * MP + e] = f2bf(v.x);
                    fbT[(cg + c4 + 1) * MP + e] = f2bf(v.y);
                    fbT[(cg + c4 + 2) * MP + e] = f2bf(v.z);
                    fbT[(cg + c4 + 3) * MP + e] = f2bf(v.w);
                }
            }
        }
        __syncthreads();

        bf16x8 a0 = *(const bf16x8*)&Mt[((wave * 2 + 0) * 16 + l16) * MP + quad * 8];
        bf16x8 a1 = *(const bf16x8*)&Mt[((wave * 2 + 1) * 16 + l16) * MP + quad * 8];
#pragma unroll
        for (int ct = 0; ct < CT; ++ct) {
            bf16x8 b = *(const bf16x8*)&fbT[(ct * 16 + l16) * MP + quad * 8];
            acc[0][ct] = __builtin_amdgcn_mfma_f32_16x16x32_bf16(a0, b, acc[0][ct], 0, 0, 0);
            acc[1][ct] = __builtin_amdgcn_mfma_f32_16x16x32_bf16(a1, b, acc[1][ct], 0, 0, 0);
        }
    }

    unsigned short* To = Tb + (size_t)node * (KK_ * C);
#pragma unroll
    for (int t = 0; t < 2; ++t) {
        const int rbase = (wave * 2 + t) * 16 + quad * 4;
#pragma unroll
        for (int ct = 0; ct < CT; ++ct) {
#pragma unroll
            for (int r = 0; r < 4; ++r) {
                const int R = rbase + r;
                if (R < KK_) To[R * C + ct * 16 + l16] = f2bf(acc[t][ct][r]);
            }
        }
    }
}

// ---------------------------------------------------------------------------
// GEMM body v8: R3 PMC showed MfmaUtil pinned at 16% = the LDS-BW identity
// (1 ds_read_b128 per MFMA; 128B/cyc LDS => 15.6% ceiling -- measured 15.8).
// Fixes: (1) RF=3 row-frags per wave (M-tile 192): each B-frag feeds 3 MFMAs
// -> ceiling ~47%. (2) 2-phase double-buffered staging via global_load_lds
// (T3-minimum recipe): stage cc+1 + A(cc+1) reg-loads issued BEFORE MFMA(cc),
// one vmcnt drain at the barrier -> staging latency hides under compute.
// (3) B XOR-swizzle via pre-swizzled global source (gload_lds dest must be
// linear): LDS[row][blk] = global[row][blk^(row&7)]; reads apply same XOR ->
// bank-group bijection, conflict-free, no pad needed.
// Numerics identical to v7 (same per-output K-order).
// ---------------------------------------------------------------------------
template<int NT, int NTF, int CPB>
static __device__ __forceinline__ void gemm_body(
    unsigned char* arena,
    const unsigned short* __restrict__ A, const unsigned short* __restrict__ Bt,
    unsigned short* __restrict__ P, int M, int Kd, int chunk, int zhalf)
{
    constexpr int COLS   = 64;
    constexpr int RF     = 3;
    constexpr int NFRAG  = NT / 16;
    constexpr int CSP    = NT + 8;
    constexpr int BUNITS = NT * COLS / 8;

    using bf16x8 = __attribute__((ext_vector_type(8))) short;
    using f32x4  = __attribute__((ext_vector_type(4))) float;

    unsigned short* Bs0 = (unsigned short*)arena;
    unsigned short* Bs1 = (unsigned short*)(arena + NT * COLS * 2);

    const int tid  = threadIdx.x;
    const int wave = tid >> 6;
    const int lane = tid & 63;
    const int quad = lane >> 4;
    const int l16  = lane & 15;
    const int m0   = blockIdx.x * MTILE_;
    const unsigned short* Bp = Bt + (size_t)zhalf * NT * Kd;
    const int kbase = chunk * CPB * COLS;
    const int ccmax = min(CPB, (Kd - kbase + COLS - 1) / COLS);

    bool avalid[RF]; const unsigned short* Ap[RF];
#pragma unroll
    for (int t = 0; t < RF; ++t) {
        const int ar = m0 + (wave * RF + t) * 16 + l16;
        avalid[t] = ar < M;
        Ap[t] = A + (size_t)(avalid[t] ? ar : 0) * Kd;
    }

    f32x4 acc[RF][NFRAG];
#pragma unroll
    for (int t = 0; t < RF; ++t)
#pragma unroll
        for (int f = 0; f < NFRAG; ++f) acc[t][f] = (f32x4){0.f, 0.f, 0.f, 0.f};

    uint4 afC[RF][2], afN[RF][2];

    auto STAGE = [&](int cc, unsigned short* B) {
        const int k0 = kbase + cc * COLS;
#pragma unroll
        for (int i = 0; i < BUNITS / 256; ++i) {
            const int u   = tid + i * 256;
            const int row = u >> 3;
            const int blk = (u & 7) ^ (row & 7);     // pre-swizzled source
            const unsigned short* g = Bp + (size_t)row * Kd + k0 + blk * 8;
            __builtin_amdgcn_global_load_lds(
                (const __attribute__((address_space(1))) void*)g,
                (__attribute__((address_space(3))) void*)(B + u * 8),
                16, 0, 0);
        }
    };
    auto LOADA = [&](int cc, uint4 (&af)[RF][2]) {
        const int k0 = kbase + cc * COLS;
#pragma unroll
        for (int t = 0; t < RF; ++t)
#pragma unroll
            for (int s = 0; s < 2; ++s) {
                const int k = k0 + s * 32 + quad * 8;
                af[t][s] = (avalid[t] && k < Kd) ? *(const uint4*)(Ap[t] + k)
                                                 : make_uint4(0u, 0u, 0u, 0u);
            }
    };

    STAGE(0, Bs0);
    LOADA(0, afC);
    __syncthreads();

    for (int cc = 0; cc < ccmax; ++cc) {
        unsigned short* bc = (cc & 1) ? Bs1 : Bs0;
        unsigned short* bn = (cc & 1) ? Bs0 : Bs1;
        const bool havenext = (cc + 1 < ccmax);
        if (havenext) { STAGE(cc + 1, bn); LOADA(cc + 1, afN); }
#pragma unroll
        for (int s = 0; s < 2; ++s)
#pragma unroll
            for (int f = 0; f < NFRAG; ++f) {
                bf16x8 bv = *(const bf16x8*)
                    &bc[(f * 16 + l16) * COLS + (((s * 4 + quad) ^ (l16 & 7)) * 8)];
#pragma unroll
                for (int t = 0; t < RF; ++t)
                    acc[t][f] = __builtin_amdgcn_mfma_f32_16x16x32_bf16(
                        __builtin_bit_cast(bf16x8, afC[t][s]), bv, acc[t][f], 0, 0, 0);
            }
        __syncthreads();
        if (havenext) {
#pragma unroll
            for (int t = 0; t < RF; ++t) {
                afC[t][0] = afN[t][0]; afC[t][1] = afN[t][1];
            }
        }
    }

    // epilogue: 3 chunked transpose passes of 64 rows through the arena
    unsigned short* Cs = (unsigned short*)arena;   // [64][CSP]
    unsigned short* Pc = P + ((size_t)chunk * M + m0) * NTF + zhalf * NT;
#pragma unroll
    for (int p = 0; p < 3; ++p) {
        __syncthreads();
#pragma unroll
        for (int t = 0; t < RF; ++t) {
            const int fr = wave * RF + t;
            if ((fr >> 2) == p) {
                const int rb = (fr & 3) * 16 + quad * 4;
#pragma unroll
                for (int f = 0; f < NFRAG; ++f) {
                    const int col = f * 16 + l16;
#pragma unroll
                    for (int r = 0; r < 4; ++r)
                        Cs[(rb + r) * CSP + col] = f2bf(acc[t][f][r]);
                }
            }
        }
        __syncthreads();
        constexpr int UNITS = 64 * NT / 8;
        for (int u = tid; u < UNITS; u += 256) {
            const int row = (u * 8) / NT, col = (u * 8) % NT;
            if (m0 + p * 64 + row < M)
                *(uint4*)&Pc[(size_t)(p * 64 + row) * NTF + col] =
                    *(const uint4*)&Cs[row * CSP + col];
        }
    }
}

// Merged GEMM: blockIdx.y < CH2_ -> h-chunk; else x-(chunk,half).
__global__ __launch_bounds__(256) void gemm_all_kernel(
    const unsigned short* __restrict__ Tx, const unsigned short* __restrict__ B1t,
    unsigned short* __restrict__ P1,
    const unsigned short* __restrict__ Th, const unsigned short* __restrict__ B2t,
    unsigned short* __restrict__ P2)
{
    __shared__ __align__(16) unsigned char arena[2 * 128 * 64 * 2];
    const int y = blockIdx.y;
    if (y < CH2_) {
        gemm_body<128, 128, CPB_>(arena, Th, B2t, P2, NN_, KK_ * CHID_, y, 0);
    } else {
        const int g = y - CH2_;            // 0..7 -> (chunk 0..3, half 0..1)
        gemm_body<96, 192, CPB_>(arena, Tx, B1t, P1, NN_, KK_ * CIN_, g >> 1, g & 1);
    }
}

// ---------------------------------------------------------------------------
// Epilogue: one wave per node, lane = output channel. Sums bf16 split-K
// partials (L2-resident), mean-agg, root GEMV, GRU gates.
// ---------------------------------------------------------------------------
__global__ __launch_bounds__(256) void epilogue_kernel(
    const unsigned short* __restrict__ P1, const unsigned short* __restrict__ P2,
    const int* __restrict__ offs,
    const float* __restrict__ x, const float* __restrict__ hidden,
    const float* __restrict__ root_xr, const float* __restrict__ root_hr,
    const float* __restrict__ root_xz, const float* __restrict__ root_hz,
    const float* __restrict__ root_xn,
    const float* __restrict__ b_xr, const float* __restrict__ b_hr,
    const float* __restrict__ b_xz, const float* __restrict__ b_hz,
    const float* __restrict__ b_xn,
    float* __restrict__ out)
{
    __shared__ float xsh[4][32];
    __shared__ float hsh[4][64];
    const int w = threadIdx.x >> 6;
    const int o = threadIdx.x & 63;
    const int m = blockIdx.x * 4 + w;
    if (m >= NN_) return;

    if (o < 32) xsh[w][o] = x[(size_t)m * 32 + o];
    const float hval = hidden[(size_t)m * 64 + o];
    hsh[w][o] = hval;

    float axr = 0.f, axz = 0.f, axn = 0.f;
#pragma unroll
    for (int c = 0; c < CH1_; ++c) {
        const unsigned short* p = P1 + ((size_t)c * NN_ + m) * 192;
        axr += bf2f(p[o]); axz += bf2f(p[64 + o]); axn += bf2f(p[128 + o]);
    }
    float ahr = 0.f, ahz = 0.f;
#pragma unroll
    for (int c = 0; c < CH2_; ++c) {
        const unsigned short* p = P2 + ((size_t)c * NN_ + m) * 128;
        ahr += bf2f(p[o]); ahz += bf2f(p[64 + o]);
    }

    const int   dg   = offs[m + 1] - offs[m];
    const float dinv = 1.0f / fmaxf((float)dg, 1.0f);
    axr *= dinv; axz *= dinv; axn *= dinv; ahr *= dinv; ahz *= dinv;

    float sxr = 0.f, sxz = 0.f, sxn = 0.f;
#pragma unroll
    for (int c = 0; c < CIN_; ++c) {
        float xv = xsh[w][c];
        sxr += xv * root_xr[c * 64 + o];
        sxz += xv * root_xz[c * 64 + o];
        sxn += xv * root_xn[c * 64 + o];
    }
    float shr = 0.f, shz = 0.f;
#pragma unroll
    for (int c = 0; c < CHID_; ++c) {
        float hv = hsh[w][c];
        shr += hv * root_hr[c * 64 + o];
        shz += hv * root_hz[c * 64 + o];
    }

    const float conv_xr = axr + sxr + b_xr[o];
    const float conv_xz = axz + sxz + b_xz[o];
    const float conv_xn = axn + sxn + b_xn[o];
    const float hr_out  = ahr + shr + b_hr[o];
    const float conv_hz = ahz + shz + b_hz[o];

    const float rg = 1.0f / (1.0f + expf(-(conv_xr + hr_out)));
    const float zg = 1.0f / (1.0f + expf(-(conv_xz + conv_hz)));
    const float ng = tanhf(conv_xn + rg * hr_out);
    out[(size_t)m * 64 + o] = (1.0f - zg) * ng + zg * hval;
}

// ---------------------------------------------------------------------------
extern "C" void kernel_launch(void* const* d_in, const int* in_sizes, int n_in,
                              void* d_out, int out_size, void* d_ws, size_t ws_size,
                              hipStream_t stream)
{
    const float* x       = (const float*)d_in[0];
    const float* hidden  = (const float*)d_in[1];
    const int*   ei      = (const int*)  d_in[2];
    const float* attr    = (const float*)d_in[3];
    const float* W_xr    = (const float*)d_in[4];
    const float* root_xr = (const float*)d_in[5];
    const float* b_xr    = (const float*)d_in[6];
    const float* W_hr    = (const float*)d_in[7];
    const float* root_hr = (const float*)d_in[8];
    const float* b_hr    = (const float*)d_in[9];
    const float* W_xz    = (const float*)d_in[10];
    const float* root_xz = (const float*)d_in[11];
    const float* b_xz    = (const float*)d_in[12];
    const float* W_hz    = (const float*)d_in[13];
    const float* root_hz = (const float*)d_in[14];
    const float* b_hz    = (const float*)d_in[15];
    const float* W_xn    = (const float*)d_in[16];
    const float* root_xn = (const float*)d_in[17];
    const float* b_xn    = (const float*)d_in[18];
    // d_in[19..21] (W_hn/root_hn/b_hn) are dead: reference reuses hr_out.
    float* out = (float*)d_out;

    // Workspace (~175 MB). No aliasing (gemm-x reads Tx while gemm-h writes
    // P2 concurrently inside gemm_all). NOTE: B1t is immediately followed by
    // B2t -- the x-GEMM tail chunk's swizzled staging reads up to ~190B past
    // B1t's end (finite bf16, canceled by A-side k<Kd zero guard).
    char* w = (char*)d_ws;
    unsigned short* Tx  = (unsigned short*)w; w += (size_t)NN_ * KK_ * CIN_  * 2;  // 48 MB
    unsigned short* Th  = (unsigned short*)w; w += (size_t)NN_ * KK_ * CHID_ * 2;  // 96 MB
    unsigned short* B1t = (unsigned short*)w; w += (size_t)192 * KK_ * CIN_  * 2;  // 1.5 MB
    unsigned short* B2t = (unsigned short*)w; w += (size_t)128 * KK_ * CHID_ * 2;  // 2.0 MB
    unsigned short* P1  = (unsigned short*)w; w += (size_t)CH1_ * NN_ * 192 * 2;   // 9.2 MB
    unsigned short* P2  = (unsigned short*)w; w += (size_t)CH2_ * NN_ * 128 * 2;   // 12.3 MB
    float4* meta_s = (float4*)w; w += (size_t)EE_ * 16;                            // 3.07 MB
    int* src_s  = (int*)w;   w += (size_t)EE_ * 4;                                 // 0.77 MB
    int* deg    = (int*)w;   w += (size_t)NN_ * 4;
    int* offs   = (int*)w;   w += (size_t)(NN_ + 4) * 4;
    int* cursor = (int*)w;   w += (size_t)NN_ * 4;

    const int MT = (NN_ + MTILE_ - 1) / MTILE_;   // 32 m-tiles

    hipMemsetAsync(deg, 0, (size_t)NN_ * 4, stream);

    // ---- launch 1: deg count + weight packs (independent, merged) ----
    const int PACKB = (PK1_ + PK2_ + 255) / 256;
    count_pack_kernel<<<CB_ + PACKB, 256, 0, stream>>>(
        ei, deg, W_xr, W_xz, W_xn, W_hr, W_hz, B1t, B2t);

    // ---- scan + sorted edge records ----
    scan_kernel<<<1, 1024, 0, stream>>>(deg, offs, cursor);
    prep_kernel<<<(EE_ + 255) / 256, 256, 0, stream>>>(ei, attr, cursor, meta_s, src_s);

    // ---- T builds: MFMA formulation ----
    build_T_kernel<CHID_><<<NN_, 256, 0, stream>>>(meta_s, src_s, hidden, offs, Th);
    build_T_kernel<CIN_><<<NN_, 256, 0, stream>>>(meta_s, src_s, x, offs, Tx);

    // ---- merged x+h GEMMs (co-resident, one launch) ----
    gemm_all_kernel<<<dim3(MT, CH2_ + 2 * CH1_), 256, 0, stream>>>(
        Tx, B1t, P1, Th, B2t, P2);

    // ---- fused reduce + GRU epilogue (wave per node) ----
    epilogue_kernel<<<(NN_ + 3) / 4, 256, 0, stream>>>(
        P1, P2, offs, x, hidden,
        root_xr, root_hr, root_xz, root_hz, root_xn,
        b_xr, b_hr, b_xz, b_hz, b_xn, out);
}

// Round 5
// 249.937 us; speedup vs baseline: 4.0770x; 1.0012x over previous
//
#include <hip/hip_runtime.h>
#include <math.h>

#define NN_   6000
#define EE_   192000
#define CIN_  32
#define CHID_ 64
#define KK_   125   // 5^3 spline kernel cells
#define EB_   32    // edge batch per block in build_T (= MFMA K)
#define CH1_  4     // x-GEMM outer chunks (each = CPB*64 cols)
#define CH2_  8     // h-GEMM outer chunks
#define CPB_  16    // k-chunks per GEMM block (64 cols each)
#define MTILE_ 192  // GEMM m-tile (4 waves x 3 row-frags x 16)

// fp32 -> bf16 round-to-nearest-even
static __device__ __forceinline__ unsigned short f2bf(float f) {
    unsigned int u = __builtin_bit_cast(unsigned int, f);
    u += 0x7fff + ((u >> 16) & 1);
    return (unsigned short)(u >> 16);
}
static __device__ __forceinline__ float bf2f(unsigned short h) {
    unsigned int u = ((unsigned int)h) << 16;
    return __builtin_bit_cast(float, u);
}

// ---------------------------------------------------------------------------
// Launch 1: deg count + weight packs (independent work, one launch).
// ---------------------------------------------------------------------------
#define PK1_ (192 * KK_ * CIN_)    // 768000
#define PK2_ (128 * KK_ * CHID_)   // 1024000
#define CB_  ((EE_ + 255) / 256)   // 750 count blocks
__global__ __launch_bounds__(256) void count_pack_kernel(
    const int* __restrict__ ei, int* __restrict__ deg,
    const float* __restrict__ W_xr, const float* __restrict__ W_xz,
    const float* __restrict__ W_xn, const float* __restrict__ W_hr,
    const float* __restrict__ W_hz,
    unsigned short* __restrict__ B1t, unsigned short* __restrict__ B2t)
{
    const int b = blockIdx.x;
    if (b < CB_) {
        int e = b * 256 + threadIdx.x;
        if (e < EE_) atomicAdd(&deg[ei[EE_ + e]], 1);
        return;
    }
    int gid = (b - CB_) * 256 + threadIdx.x;
    if (gid < PK1_) {
        int n  = gid / (KK_ * CIN_);
        int kk = gid % (KK_ * CIN_);
        int conv = n >> 6, o = n & 63;
        const float* W = (conv == 0) ? W_xr : ((conv == 1) ? W_xz : W_xn);
        B1t[gid] = f2bf(W[(size_t)kk * 64 + o]);
    } else if (gid < PK1_ + PK2_) {
        int g2 = gid - PK1_;
        int n  = g2 / (KK_ * CHID_);
        int kk = g2 % (KK_ * CHID_);
        int conv = n >> 6, o = n & 63;
        const float* W = (conv == 0) ? W_hr : W_hz;
        B2t[g2] = f2bf(W[(size_t)kk * 64 + o]);
    }
}

__global__ __launch_bounds__(1024) void scan_kernel(
    const int* __restrict__ deg, int* __restrict__ offs, int* __restrict__ cursor)
{
    __shared__ int part[1024];
    const int tid = threadIdx.x;
    const int CH = (NN_ + 1023) / 1024;   // 6
    const int base = tid * CH;
    int loc[CH];
    int s = 0;
#pragma unroll
    for (int i = 0; i < CH; ++i) {
        int v = (base + i < NN_) ? deg[base + i] : 0;
        loc[i] = s; s += v;
    }
    part[tid] = s;
    __syncthreads();
    for (int off = 1; off < 1024; off <<= 1) {
        int v = (tid >= off) ? part[tid - off] : 0;
        __syncthreads();
        part[tid] += v;
        __syncthreads();
    }
    const int pre = (tid > 0) ? part[tid - 1] : 0;
#pragma unroll
    for (int i = 0; i < CH; ++i) {
        if (base + i < NN_) {
            offs[base + i]   = pre + loc[i];
            cursor[base + i] = pre + loc[i];
        }
    }
    if (tid == 1023) offs[NN_] = part[1023];
}

// Compute per-edge spline meta ONCE, scattered to dst-sorted position.
__global__ __launch_bounds__(256) void prep_kernel(
    const int* __restrict__ ei, const float* __restrict__ attr,
    int* __restrict__ cursor, float4* __restrict__ meta_s, int* __restrict__ src_s)
{
    int e = blockIdx.x * 256 + threadIdx.x;
    if (e >= EE_) return;
    const int dst = ei[EE_ + e];
    const int p   = atomicAdd(&cursor[dst], 1);
    float f[3]; int i0[3];
#pragma unroll
    for (int d = 0; d < 3; ++d) {
        float u  = attr[e * 3 + d] * 4.0f;
        float fl = floorf(u);
        fl = fminf(fmaxf(fl, 0.0f), 3.0f);
        i0[d] = (int)fl;
        f[d]  = u - fl;
    }
    meta_s[p] = make_float4(f[0], f[1], f[2],
        __int_as_float(i0[0] * 25 + i0[1] * 5 + i0[2]));
    src_s[p] = ei[e];
}

// ---------------------------------------------------------------------------
// Per-node T build v6 (R3-proven): dense-MFMA reformulation.
// ---------------------------------------------------------------------------
template<int C>
__global__ __launch_bounds__(256) void build_T_kernel(
    const float4* __restrict__ meta_s, const int* __restrict__ src_s,
    const float* __restrict__ feat, const int* __restrict__ offs,
    unsigned short* __restrict__ Tb)
{
    constexpr int MP  = 40;              // padded row stride (shorts)
    constexpr int CT  = C / 16;          // B col-tiles (4 or 2)
    constexpr int CPT = C / 8;           // channels per fbT-fill thread
    using bf16x8 = __attribute__((ext_vector_type(8))) short;
    using f32x4  = __attribute__((ext_vector_type(4))) float;

    __shared__ __align__(16) unsigned short Mt [128 * MP];  // [cell][edge] bf16
    __shared__ __align__(16) unsigned short fbT[C   * MP];  // [channel][edge] bf16
    __shared__ int s_src[EB_];

    const int tid  = threadIdx.x;
    const int wave = tid >> 6;
    const int lane = tid & 63;
    const int quad = lane >> 4;
    const int l16  = lane & 15;
    const int node = blockIdx.x;

    // zero fbT once: stale LDS may be NaN-patterned; NaN*0 = NaN in MFMA
    for (int i = tid; i < C * MP / 8; i += 256)
        ((uint4*)fbT)[i] = make_uint4(0u, 0u, 0u, 0u);

    const int j0 = offs[node], j1 = offs[node + 1];

    f32x4 acc[2][CT];
#pragma unroll
    for (int t = 0; t < 2; ++t)
#pragma unroll
        for (int ct = 0; ct < CT; ++ct) acc[t][ct] = (f32x4){0.f, 0.f, 0.f, 0.f};

    for (int jb = j0; jb < j1; jb += EB_) {
        const int m = min(EB_, j1 - jb);

        __syncthreads();   // prev batch MFMA reads done
        for (int i = tid; i < 128 * MP / 8; i += 256)
            ((uint4*)Mt)[i] = make_uint4(0u, 0u, 0u, 0u);
        if (tid < m) s_src[tid] = src_s[jb + tid];
        __syncthreads();

        // build M: thread-per-edge, 8 distinct rows of own column (race-free)
        if (tid < m) {
            const float4 mt = meta_s[jb + tid];
            const int base = __float_as_int(mt.w);
            const float f0 = mt.x, f1 = mt.y, f2 = mt.z;
            const float g0 = 1.f - f0, g1 = 1.f - f1, g2 = 1.f - f2;
            const float bb[8] = {g0*g1*g2, f0*g1*g2, g0*f1*g2, f0*f1*g2,
                                 g0*g1*f2, f0*g1*f2, g0*f1*f2, f0*f1*f2};
            const int oc[8] = {0, 25, 5, 30, 1, 26, 6, 31};
#pragma unroll
            for (int s = 0; s < 8; ++s)
                Mt[(base + oc[s]) * MP + tid] = f2bf(bb[s]);
        }
        // build B = feat^T: 8 threads per edge, CPT channels each
        {
            const int e = tid >> 3, cg = (tid & 7) * CPT;
            if (e < m) {
                const float* fr = &feat[(size_t)s_src[e] * C + cg];
#pragma unroll
                for (int c4 = 0; c4 < CPT; c4 += 4) {
                    float4 v = *(const float4*)(fr + c4);
                    fbT[(cg + c4 + 0) * MP + e] = f2bf(v.x);
                    fbT[(cg + c4 + 1) * MP + e] = f2bf(v.y);
                    fbT[(cg + c4 + 2) * MP + e] = f2bf(v.z);
                    fbT[(cg + c4 + 3) * MP + e] = f2bf(v.w);
                }
            }
        }
        __syncthreads();

        bf16x8 a0 = *(const bf16x8*)&Mt[((wave * 2 + 0) * 16 + l16) * MP + quad * 8];
        bf16x8 a1 = *(const bf16x8*)&Mt[((wave * 2 + 1) * 16 + l16) * MP + quad * 8];
#pragma unroll
        for (int ct = 0; ct < CT; ++ct) {
            bf16x8 b = *(const bf16x8*)&fbT[(ct * 16 + l16) * MP + quad * 8];
            acc[0][ct] = __builtin_amdgcn_mfma_f32_16x16x32_bf16(a0, b, acc[0][ct], 0, 0, 0);
            acc[1][ct] = __builtin_amdgcn_mfma_f32_16x16x32_bf16(a1, b, acc[1][ct], 0, 0, 0);
        }
    }

    unsigned short* To = Tb + (size_t)node * (KK_ * C);
#pragma unroll
    for (int t = 0; t < 2; ++t) {
        const int rbase = (wave * 2 + t) * 16 + quad * 4;
#pragma unroll
        for (int ct = 0; ct < CT; ++ct) {
#pragma unroll
            for (int r = 0; r < 4; ++r) {
                const int R = rbase + r;
                if (R < KK_) To[R * C + ct * 16 + l16] = f2bf(acc[t][ct][r]);
            }
        }
    }
}

// ---------------------------------------------------------------------------
// GEMM body v9: R4 PMC post-mortem -- swizzle worked (conflicts 5.4M->84K)
// yet MfmaUtil stayed 15%: the binding constraint was never LDS BW, it is
// the A-operand ROW-SCATTER (per-lane uint4 at stride Kd*2B touches 64
// cache lines = ~512B of L2-line traffic per MFMA in BOTH R3 and R4 ->
// ~15% ceiling at ~56 B/cyc/CU L2 supply). Fix: A is now staged through
// LDS via COALESCED global_load_lds (rows contiguous in K, lines fully
// used); A-frags read from LDS with the same XOR swizzle as B (A-frag
// read is a column-slice -> needs it). LOADA deleted. Per-MFMA global
// traffic 512B -> ~53B; new co-limiters: LDS reads (~33% ceiling) and
// coalesced L2 (~32%). K-tail guard moved to A staging (zero-fill OOB
// k-blocks; B-side garbage then multiplies zero). LDS 80KB/block ->
// exactly 2 blocks/CU. Numerics bit-identical to v8 (same K-order).
// ---------------------------------------------------------------------------
template<int NT, int NTF, int CPB>
static __device__ __forceinline__ void gemm_body(
    unsigned char* arena,
    const unsigned short* __restrict__ A, const unsigned short* __restrict__ Bt,
    unsigned short* __restrict__ P, int M, int Kd, int chunk, int zhalf)
{
    constexpr int COLS   = 64;
    constexpr int RF     = 3;
    constexpr int NFRAG  = NT / 16;
    constexpr int CSP    = NT + 8;
    constexpr int ABYTES = MTILE_ * COLS * 2;      // 24576
    constexpr int BBYTES = NT * COLS * 2;          // 16384 / 12288
    constexpr int AUNITS = MTILE_ * COLS / 8;      // 1536 (6 per thread)
    constexpr int BUNITS = NT * COLS / 8;          // 1024 / 768

    using bf16x8 = __attribute__((ext_vector_type(8))) short;
    using f32x4  = __attribute__((ext_vector_type(4))) float;

    unsigned short* As0 = (unsigned short*)(arena);
    unsigned short* As1 = (unsigned short*)(arena + ABYTES);
    unsigned short* Bs0 = (unsigned short*)(arena + 2 * ABYTES);
    unsigned short* Bs1 = (unsigned short*)(arena + 2 * ABYTES + BBYTES);

    const int tid  = threadIdx.x;
    const int wave = tid >> 6;
    const int lane = tid & 63;
    const int quad = lane >> 4;
    const int l16  = lane & 15;
    const int m0   = blockIdx.x * MTILE_;
    const unsigned short* Bp = Bt + (size_t)zhalf * NT * Kd;
    const int kbase = chunk * CPB * COLS;
    const int ccmax = min(CPB, (Kd - kbase + COLS - 1) / COLS);

    f32x4 acc[RF][NFRAG];
#pragma unroll
    for (int t = 0; t < RF; ++t)
#pragma unroll
        for (int f = 0; f < NFRAG; ++f) acc[t][f] = (f32x4){0.f, 0.f, 0.f, 0.f};

    // LDS[row][b] = global blk (b ^ (row&7)); reader of global blk G uses
    // b = G^(row&7). A rows may run past M (reads land in adjacent mapped
    // workspace; those acc rows are never stored). K-tail: zero-fill A units
    // whose k-block exceeds Kd -- B-side garbage then contributes 0.
    auto STAGE = [&](int cc, unsigned short* Abuf, unsigned short* Bbuf) {
        const int k0 = kbase + cc * COLS;
#pragma unroll
        for (int i = 0; i < AUNITS / 256; ++i) {
            const int u    = tid + i * 256;
            const int row  = u >> 3;
            const int gblk = (u & 7) ^ (row & 7);
            const int k    = k0 + gblk * 8;
            if (k + 8 <= Kd) {
                const unsigned short* g = A + (size_t)(m0 + row) * Kd + k;
                __builtin_amdgcn_global_load_lds(
                    (const __attribute__((address_space(1))) void*)g,
                    (__attribute__((address_space(3))) void*)(Abuf + u * 8),
                    16, 0, 0);
            } else {
                *(uint4*)(Abuf + u * 8) = make_uint4(0u, 0u, 0u, 0u);
            }
        }
#pragma unroll
        for (int i = 0; i < BUNITS / 256; ++i) {
            const int u    = tid + i * 256;
            const int row  = u >> 3;
            const int gblk = (u & 7) ^ (row & 7);
            const unsigned short* g = Bp + (size_t)row * Kd + k0 + gblk * 8;
            __builtin_amdgcn_global_load_lds(
                (const __attribute__((address_space(1))) void*)g,
                (__attribute__((address_space(3))) void*)(Bbuf + u * 8),
                16, 0, 0);
        }
    };

    STAGE(0, As0, Bs0);
    __syncthreads();

    for (int cc = 0; cc < ccmax; ++cc) {
        unsigned short* Ac = (cc & 1) ? As1 : As0;
        unsigned short* Bc = (cc & 1) ? Bs1 : Bs0;
        if (cc + 1 < ccmax)
            STAGE(cc + 1, (cc & 1) ? As0 : As1, (cc & 1) ? Bs0 : Bs1);
#pragma unroll
        for (int s = 0; s < 2; ++s) {
            bf16x8 av[RF];
#pragma unroll
            for (int t = 0; t < RF; ++t) {
                const int row = (wave * RF + t) * 16 + l16;
                av[t] = *(const bf16x8*)
                    &Ac[row * COLS + (((s * 4 + quad) ^ (l16 & 7)) * 8)];
            }
#pragma unroll
            for (int f = 0; f < NFRAG; ++f) {
                bf16x8 bv = *(const bf16x8*)
                    &Bc[(f * 16 + l16) * COLS + (((s * 4 + quad) ^ (l16 & 7)) * 8)];
#pragma unroll
                for (int t = 0; t < RF; ++t)
                    acc[t][f] = __builtin_amdgcn_mfma_f32_16x16x32_bf16(
                        av[t], bv, acc[t][f], 0, 0, 0);
            }
        }
        __syncthreads();
    }

    // epilogue: 3 chunked transpose passes of 64 rows through the arena
    unsigned short* Cs = (unsigned short*)arena;   // [64][CSP]
    unsigned short* Pc = P + ((size_t)chunk * M + m0) * NTF + zhalf * NT;
#pragma unroll
    for (int p = 0; p < 3; ++p) {
        __syncthreads();
#pragma unroll
        for (int t = 0; t < RF; ++t) {
            const int fr = wave * RF + t;
            if ((fr >> 2) == p) {
                const int rb = (fr & 3) * 16 + quad * 4;
#pragma unroll
                for (int f = 0; f < NFRAG; ++f) {
                    const int col = f * 16 + l16;
#pragma unroll
                    for (int r = 0; r < 4; ++r)
                        Cs[(rb + r) * CSP + col] = f2bf(acc[t][f][r]);
                }
            }
        }
        __syncthreads();
        constexpr int UNITS = 64 * NT / 8;
        for (int u = tid; u < UNITS; u += 256) {
            const int row = (u * 8) / NT, col = (u * 8) % NT;
            if (m0 + p * 64 + row < M)
                *(uint4*)&Pc[(size_t)(p * 64 + row) * NTF + col] =
                    *(const uint4*)&Cs[row * CSP + col];
        }
    }
}

// Merged GEMM: blockIdx.y < CH2_ -> h-chunk; else x-(chunk,half).
__global__ __launch_bounds__(256) void gemm_all_kernel(
    const unsigned short* __restrict__ Tx, const unsigned short* __restrict__ B1t,
    unsigned short* __restrict__ P1,
    const unsigned short* __restrict__ Th, const unsigned short* __restrict__ B2t,
    unsigned short* __restrict__ P2)
{
    // 2*A(24576) + 2*B(16384) = 81920 B -> exactly 2 blocks per 160 KiB CU
    __shared__ __align__(16) unsigned char arena[2 * 24576 + 2 * 16384];
    const int y = blockIdx.y;
    if (y < CH2_) {
        gemm_body<128, 128, CPB_>(arena, Th, B2t, P2, NN_, KK_ * CHID_, y, 0);
    } else {
        const int g = y - CH2_;            // 0..7 -> (chunk 0..3, half 0..1)
        gemm_body<96, 192, CPB_>(arena, Tx, B1t, P1, NN_, KK_ * CIN_, g >> 1, g & 1);
    }
}

// ---------------------------------------------------------------------------
// Epilogue: one wave per node, lane = output channel. Sums bf16 split-K
// partials (L2-resident), mean-agg, root GEMV, GRU gates.
// ---------------------------------------------------------------------------
__global__ __launch_bounds__(256) void epilogue_kernel(
    const unsigned short* __restrict__ P1, const unsigned short* __restrict__ P2,
    const int* __restrict__ offs,
    const float* __restrict__ x, const float* __restrict__ hidden,
    const float* __restrict__ root_xr, const float* __restrict__ root_hr,
    const float* __restrict__ root_xz, const float* __restrict__ root_hz,
    const float* __restrict__ root_xn,
    const float* __restrict__ b_xr, const float* __restrict__ b_hr,
    const float* __restrict__ b_xz, const float* __restrict__ b_hz,
    const float* __restrict__ b_xn,
    float* __restrict__ out)
{
    __shared__ float xsh[4][32];
    __shared__ float hsh[4][64];
    const int w = threadIdx.x >> 6;
    const int o = threadIdx.x & 63;
    const int m = blockIdx.x * 4 + w;
    if (m >= NN_) return;

    if (o < 32) xsh[w][o] = x[(size_t)m * 32 + o];
    const float hval = hidden[(size_t)m * 64 + o];
    hsh[w][o] = hval;

    float axr = 0.f, axz = 0.f, axn = 0.f;
#pragma unroll
    for (int c = 0; c < CH1_; ++c) {
        const unsigned short* p = P1 + ((size_t)c * NN_ + m) * 192;
        axr += bf2f(p[o]); axz += bf2f(p[64 + o]); axn += bf2f(p[128 + o]);
    }
    float ahr = 0.f, ahz = 0.f;
#pragma unroll
    for (int c = 0; c < CH2_; ++c) {
        const unsigned short* p = P2 + ((size_t)c * NN_ + m) * 128;
        ahr += bf2f(p[o]); ahz += bf2f(p[64 + o]);
    }

    const int   dg   = offs[m + 1] - offs[m];
    const float dinv = 1.0f / fmaxf((float)dg, 1.0f);
    axr *= dinv; axz *= dinv; axn *= dinv; ahr *= dinv; ahz *= dinv;

    float sxr = 0.f, sxz = 0.f, sxn = 0.f;
#pragma unroll
    for (int c = 0; c < CIN_; ++c) {
        float xv = xsh[w][c];
        sxr += xv * root_xr[c * 64 + o];
        sxz += xv * root_xz[c * 64 + o];
        sxn += xv * root_xn[c * 64 + o];
    }
    float shr = 0.f, shz = 0.f;
#pragma unroll
    for (int c = 0; c < CHID_; ++c) {
        float hv = hsh[w][c];
        shr += hv * root_hr[c * 64 + o];
        shz += hv * root_hz[c * 64 + o];
    }

    const float conv_xr = axr + sxr + b_xr[o];
    const float conv_xz = axz + sxz + b_xz[o];
    const float conv_xn = axn + sxn + b_xn[o];
    const float hr_out  = ahr + shr + b_hr[o];
    const float conv_hz = ahz + shz + b_hz[o];

    const float rg = 1.0f / (1.0f + expf(-(conv_xr + hr_out)));
    const float zg = 1.0f / (1.0f + expf(-(conv_xz + conv_hz)));
    const float ng = tanhf(conv_xn + rg * hr_out);
    out[(size_t)m * 64 + o] = (1.0f - zg) * ng + zg * hval;
}

// ---------------------------------------------------------------------------
extern "C" void kernel_launch(void* const* d_in, const int* in_sizes, int n_in,
                              void* d_out, int out_size, void* d_ws, size_t ws_size,
                              hipStream_t stream)
{
    const float* x       = (const float*)d_in[0];
    const float* hidden  = (const float*)d_in[1];
    const int*   ei      = (const int*)  d_in[2];
    const float* attr    = (const float*)d_in[3];
    const float* W_xr    = (const float*)d_in[4];
    const float* root_xr = (const float*)d_in[5];
    const float* b_xr    = (const float*)d_in[6];
    const float* W_hr    = (const float*)d_in[7];
    const float* root_hr = (const float*)d_in[8];
    const float* b_hr    = (const float*)d_in[9];
    const float* W_xz    = (const float*)d_in[10];
    const float* root_xz = (const float*)d_in[11];
    const float* b_xz    = (const float*)d_in[12];
    const float* W_hz    = (const float*)d_in[13];
    const float* root_hz = (const float*)d_in[14];
    const float* b_hz    = (const float*)d_in[15];
    const float* W_xn    = (const float*)d_in[16];
    const float* root_xn = (const float*)d_in[17];
    const float* b_xn    = (const float*)d_in[18];
    // d_in[19..21] (W_hn/root_hn/b_hn) are dead: reference reuses hr_out.
    float* out = (float*)d_out;

    // Workspace (~175 MB). No aliasing (gemm-x reads Tx while gemm-h writes
    // P2 concurrently inside gemm_all). NOTE: A/B staging may read a few
    // rows past its region's end (OOB M rows / K-tail swizzled blocks) --
    // all land in adjacent mapped workspace; A K-tail is zero-filled so
    // those products are exactly 0, and OOB M rows are never stored.
    char* w = (char*)d_ws;
    unsigned short* Tx  = (unsigned short*)w; w += (size_t)NN_ * KK_ * CIN_  * 2;  // 48 MB
    unsigned short* Th  = (unsigned short*)w; w += (size_t)NN_ * KK_ * CHID_ * 2;  // 96 MB
    unsigned short* B1t = (unsigned short*)w; w += (size_t)192 * KK_ * CIN_  * 2;  // 1.5 MB
    unsigned short* B2t = (unsigned short*)w; w += (size_t)128 * KK_ * CHID_ * 2;  // 2.0 MB
    unsigned short* P1  = (unsigned short*)w; w += (size_t)CH1_ * NN_ * 192 * 2;   // 9.2 MB
    unsigned short* P2  = (unsigned short*)w; w += (size_t)CH2_ * NN_ * 128 * 2;   // 12.3 MB
    float4* meta_s = (float4*)w; w += (size_t)EE_ * 16;                            // 3.07 MB
    int* src_s  = (int*)w;   w += (size_t)EE_ * 4;                                 // 0.77 MB
    int* deg    = (int*)w;   w += (size_t)NN_ * 4;
    int* offs   = (int*)w;   w += (size_t)(NN_ + 4) * 4;
    int* cursor = (int*)w;   w += (size_t)NN_ * 4;

    const int MT = (NN_ + MTILE_ - 1) / MTILE_;   // 32 m-tiles

    hipMemsetAsync(deg, 0, (size_t)NN_ * 4, stream);

    // ---- launch 1: deg count + weight packs (independent, merged) ----
    const int PACKB = (PK1_ + PK2_ + 255) / 256;
    count_pack_kernel<<<CB_ + PACKB, 256, 0, stream>>>(
        ei, deg, W_xr, W_xz, W_xn, W_hr, W_hz, B1t, B2t);

    // ---- scan + sorted edge records ----
    scan_kernel<<<1, 1024, 0, stream>>>(deg, offs, cursor);
    prep_kernel<<<(EE_ + 255) / 256, 256, 0, stream>>>(ei, attr, cursor, meta_s, src_s);

    // ---- T builds: MFMA formulation ----
    build_T_kernel<CHID_><<<NN_, 256, 0, stream>>>(meta_s, src_s, hidden, offs, Th);
    build_T_kernel<CIN_><<<NN_, 256, 0, stream>>>(meta_s, src_s, x, offs, Tx);

    // ---- merged x+h GEMMs (co-resident, one launch) ----
    gemm_all_kernel<<<dim3(MT, CH2_ + 2 * CH1_), 256, 0, stream>>>(
        Tx, B1t, P1, Th, B2t, P2);

    // ---- fused reduce + GRU epilogue (wave per node) ----
    epilogue_kernel<<<(NN_ + 3) / 4, 256, 0, stream>>>(
        P1, P2, offs, x, hidden,
        root_xr, root_hr, root_xz, root_hz, root_xn,
        b_xr, b_hr, b_xz, b_hz, b_xn, out);
}

// Round 6
// 245.234 us; speedup vs baseline: 4.1552x; 1.0192x over previous
//
#include <hip/hip_runtime.h>
#include <math.h>

#define NN_   6000
#define EE_   192000
#define CIN_  32
#define CHID_ 64
#define KK_   125   // 5^3 spline kernel cells
#define EB_   32    // edge batch per block in build_T (= MFMA K)
#define CH1_  4     // x-GEMM outer chunks (each = CPB*64 cols)
#define CH2_  8     // h-GEMM outer chunks
#define CPB_  16    // k-chunks per GEMM block (64 cols each)
#define MTILE_ 192  // GEMM m-tile (4 waves x 3 row-frags x 16)

// fp32 -> bf16 round-to-nearest-even
static __device__ __forceinline__ unsigned short f2bf(float f) {
    unsigned int u = __builtin_bit_cast(unsigned int, f);
    u += 0x7fff + ((u >> 16) & 1);
    return (unsigned short)(u >> 16);
}
static __device__ __forceinline__ float bf2f(unsigned short h) {
    unsigned int u = ((unsigned int)h) << 16;
    return __builtin_bit_cast(float, u);
}

// counted vmcnt wait: waits own wave's outstanding VMEM <= N, leaving newer
// prefetch loads in flight. "memory" clobber stops load hoisting across it;
// sched_barrier(0) stops the machine scheduler (guide rule #18).
template<int N> static __device__ __forceinline__ void vwait() {
    asm volatile("s_waitcnt vmcnt(%0)" :: "n"(N) : "memory");
    __builtin_amdgcn_sched_barrier(0);
}

// ---------------------------------------------------------------------------
// Launch 1: deg count + weight packs (independent work, one launch).
// ---------------------------------------------------------------------------
#define PK1_ (192 * KK_ * CIN_)    // 768000
#define PK2_ (128 * KK_ * CHID_)   // 1024000
#define CB_  ((EE_ + 255) / 256)   // 750 count blocks
__global__ __launch_bounds__(256) void count_pack_kernel(
    const int* __restrict__ ei, int* __restrict__ deg,
    const float* __restrict__ W_xr, const float* __restrict__ W_xz,
    const float* __restrict__ W_xn, const float* __restrict__ W_hr,
    const float* __restrict__ W_hz,
    unsigned short* __restrict__ B1t, unsigned short* __restrict__ B2t)
{
    const int b = blockIdx.x;
    if (b < CB_) {
        int e = b * 256 + threadIdx.x;
        if (e < EE_) atomicAdd(&deg[ei[EE_ + e]], 1);
        return;
    }
    int gid = (b - CB_) * 256 + threadIdx.x;
    if (gid < PK1_) {
        int n  = gid / (KK_ * CIN_);
        int kk = gid % (KK_ * CIN_);
        int conv = n >> 6, o = n & 63;
        const float* W = (conv == 0) ? W_xr : ((conv == 1) ? W_xz : W_xn);
        B1t[gid] = f2bf(W[(size_t)kk * 64 + o]);
    } else if (gid < PK1_ + PK2_) {
        int g2 = gid - PK1_;
        int n  = g2 / (KK_ * CHID_);
        int kk = g2 % (KK_ * CHID_);
        int conv = n >> 6, o = n & 63;
        const float* W = (conv == 0) ? W_hr : W_hz;
        B2t[g2] = f2bf(W[(size_t)kk * 64 + o]);
    }
}

__global__ __launch_bounds__(1024) void scan_kernel(
    const int* __restrict__ deg, int* __restrict__ offs, int* __restrict__ cursor)
{
    __shared__ int part[1024];
    const int tid = threadIdx.x;
    const int CH = (NN_ + 1023) / 1024;   // 6
    const int base = tid * CH;
    int loc[CH];
    int s = 0;
#pragma unroll
    for (int i = 0; i < CH; ++i) {
        int v = (base + i < NN_) ? deg[base + i] : 0;
        loc[i] = s; s += v;
    }
    part[tid] = s;
    __syncthreads();
    for (int off = 1; off < 1024; off <<= 1) {
        int v = (tid >= off) ? part[tid - off] : 0;
        __syncthreads();
        part[tid] += v;
        __syncthreads();
    }
    const int pre = (tid > 0) ? part[tid - 1] : 0;
#pragma unroll
    for (int i = 0; i < CH; ++i) {
        if (base + i < NN_) {
            offs[base + i]   = pre + loc[i];
            cursor[base + i] = pre + loc[i];
        }
    }
    if (tid == 1023) offs[NN_] = part[1023];
}

// Compute per-edge spline meta ONCE, scattered to dst-sorted position.
__global__ __launch_bounds__(256) void prep_kernel(
    const int* __restrict__ ei, const float* __restrict__ attr,
    int* __restrict__ cursor, float4* __restrict__ meta_s, int* __restrict__ src_s)
{
    int e = blockIdx.x * 256 + threadIdx.x;
    if (e >= EE_) return;
    const int dst = ei[EE_ + e];
    const int p   = atomicAdd(&cursor[dst], 1);
    float f[3]; int i0[3];
#pragma unroll
    for (int d = 0; d < 3; ++d) {
        float u  = attr[e * 3 + d] * 4.0f;
        float fl = floorf(u);
        fl = fminf(fmaxf(fl, 0.0f), 3.0f);
        i0[d] = (int)fl;
        f[d]  = u - fl;
    }
    meta_s[p] = make_float4(f[0], f[1], f[2],
        __int_as_float(i0[0] * 25 + i0[1] * 5 + i0[2]));
    src_s[p] = ei[e];
}

// ---------------------------------------------------------------------------
// Per-node T build v6 (R3-proven): dense-MFMA reformulation.
// ---------------------------------------------------------------------------
template<int C>
__global__ __launch_bounds__(256) void build_T_kernel(
    const float4* __restrict__ meta_s, const int* __restrict__ src_s,
    const float* __restrict__ feat, const int* __restrict__ offs,
    unsigned short* __restrict__ Tb)
{
    constexpr int MP  = 40;              // padded row stride (shorts)
    constexpr int CT  = C / 16;          // B col-tiles (4 or 2)
    constexpr int CPT = C / 8;           // channels per fbT-fill thread
    using bf16x8 = __attribute__((ext_vector_type(8))) short;
    using f32x4  = __attribute__((ext_vector_type(4))) float;

    __shared__ __align__(16) unsigned short Mt [128 * MP];  // [cell][edge] bf16
    __shared__ __align__(16) unsigned short fbT[C   * MP];  // [channel][edge] bf16
    __shared__ int s_src[EB_];

    const int tid  = threadIdx.x;
    const int wave = tid >> 6;
    const int lane = tid & 63;
    const int quad = lane >> 4;
    const int l16  = lane & 15;
    const int node = blockIdx.x;

    // zero fbT once: stale LDS may be NaN-patterned; NaN*0 = NaN in MFMA
    for (int i = tid; i < C * MP / 8; i += 256)
        ((uint4*)fbT)[i] = make_uint4(0u, 0u, 0u, 0u);

    const int j0 = offs[node], j1 = offs[node + 1];

    f32x4 acc[2][CT];
#pragma unroll
    for (int t = 0; t < 2; ++t)
#pragma unroll
        for (int ct = 0; ct < CT; ++ct) acc[t][ct] = (f32x4){0.f, 0.f, 0.f, 0.f};

    for (int jb = j0; jb < j1; jb += EB_) {
        const int m = min(EB_, j1 - jb);

        __syncthreads();   // prev batch MFMA reads done
        for (int i = tid; i < 128 * MP / 8; i += 256)
            ((uint4*)Mt)[i] = make_uint4(0u, 0u, 0u, 0u);
        if (tid < m) s_src[tid] = src_s[jb + tid];
        __syncthreads();

        // build M: thread-per-edge, 8 distinct rows of own column (race-free)
        if (tid < m) {
            const float4 mt = meta_s[jb + tid];
            const int base = __float_as_int(mt.w);
            const float f0 = mt.x, f1 = mt.y, f2 = mt.z;
            const float g0 = 1.f - f0, g1 = 1.f - f1, g2 = 1.f - f2;
            const float bb[8] = {g0*g1*g2, f0*g1*g2, g0*f1*g2, f0*f1*g2,
                                 g0*g1*f2, f0*g1*f2, g0*f1*f2, f0*f1*f2};
            const int oc[8] = {0, 25, 5, 30, 1, 26, 6, 31};
#pragma unroll
            for (int s = 0; s < 8; ++s)
                Mt[(base + oc[s]) * MP + tid] = f2bf(bb[s]);
        }
        // build B = feat^T: 8 threads per edge, CPT channels each
        {
            const int e = tid >> 3, cg = (tid & 7) * CPT;
            if (e < m) {
                const float* fr = &feat[(size_t)s_src[e] * C + cg];
#pragma unroll
                for (int c4 = 0; c4 < CPT; c4 += 4) {
                    float4 v = *(const float4*)(fr + c4);
                    fbT[(cg + c4 + 0) * MP + e] = f2bf(v.x);
                    fbT[(cg + c4 + 1) * MP + e] = f2bf(v.y);
                    fbT[(cg + c4 + 2) * MP + e] = f2bf(v.z);
                    fbT[(cg + c4 + 3) * MP + e] = f2bf(v.w);
                }
            }
        }
        __syncthreads();

        bf16x8 a0 = *(const bf16x8*)&Mt[((wave * 2 + 0) * 16 + l16) * MP + quad * 8];
        bf16x8 a1 = *(const bf16x8*)&Mt[((wave * 2 + 1) * 16 + l16) * MP + quad * 8];
#pragma unroll
        for (int ct = 0; ct < CT; ++ct) {
            bf16x8 b = *(const bf16x8*)&fbT[(ct * 16 + l16) * MP + quad * 8];
            acc[0][ct] = __builtin_amdgcn_mfma_f32_16x16x32_bf16(a0, b, acc[0][ct], 0, 0, 0);
            acc[1][ct] = __builtin_amdgcn_mfma_f32_16x16x32_bf16(a1, b, acc[1][ct], 0, 0, 0);
        }
    }

    unsigned short* To = Tb + (size_t)node * (KK_ * C);
#pragma unroll
    for (int t = 0; t < 2; ++t) {
        const int rbase = (wave * 2 + t) * 16 + quad * 4;
#pragma unroll
        for (int ct = 0; ct < CT; ++ct) {
#pragma unroll
            for (int r = 0; r < 4; ++r) {
                const int R = rbase + r;
                if (R < KK_) To[R * C + ct * 16 + l16] = f2bf(acc[t][ct][r]);
            }
        }
    }
}

// ---------------------------------------------------------------------------
// GEMM body v10: counted-vmcnt deep pipeline (T3+T4). R3/R4/R5 all pinned
// at ~16% MfmaUtil across different staging structures -- the invariant was
// the depth-1 double-buffer whose barrier drains vmcnt(0) every tile,
// exposing full HBM latency (~1400+ cyc stall vs 233 cyc MFMA). Fix:
// 3-slot rotating LDS arena (122.9 KB, 1 block/CU), prefetch distance 2
// (~80 KB in flight/CU), raw s_barrier pairs + hand-counted
// s_waitcnt vmcnt(2*LW) so tiles cc+1,cc+2 stay in flight across barriers.
// LW = per-wave loads/tile (10 h-body, 9 x-body); exact because the K-tail
// zero-fill now loads from a zeroed global scratch (keeps VMEM count) --
// a ds_write there would break the vmcnt arithmetic AND race the counted
// wait. Numerics identical to v9 (same K-order, same zero semantics).
// ---------------------------------------------------------------------------
template<int NT, int NTF, int CPB, int LW>
static __device__ __forceinline__ void gemm_body(
    unsigned short* arena,
    const unsigned short* __restrict__ A, const unsigned short* __restrict__ Bt,
    const unsigned short* __restrict__ zp,
    unsigned short* __restrict__ P, int M, int Kd, int chunk, int zhalf)
{
    constexpr int COLS   = 64;
    constexpr int RF     = 3;
    constexpr int NFRAG  = NT / 16;
    constexpr int CSP    = NT + 8;
    constexpr int ASH    = MTILE_ * COLS;          // 12288 shorts
    constexpr int SLOT   = ASH + 128 * COLS;       // 20480 shorts (h-sized B)
    constexpr int AUNITS = MTILE_ * COLS / 8;      // 1536 (6 per thread)
    constexpr int BUNITS = NT * COLS / 8;          // 1024 / 768

    using bf16x8 = __attribute__((ext_vector_type(8))) short;
    using f32x4  = __attribute__((ext_vector_type(4))) float;

    const int tid  = threadIdx.x;
    const int wave = tid >> 6;
    const int lane = tid & 63;
    const int quad = lane >> 4;
    const int l16  = lane & 15;
    const int m0   = blockIdx.x * MTILE_;
    const unsigned short* Bp = Bt + (size_t)zhalf * NT * Kd;
    const int kbase = chunk * CPB * COLS;
    const int ccmax = min(CPB, (Kd - kbase + COLS - 1) / COLS);

    f32x4 acc[RF][NFRAG];
#pragma unroll
    for (int t = 0; t < RF; ++t)
#pragma unroll
        for (int f = 0; f < NFRAG; ++f) acc[t][f] = (f32x4){0.f, 0.f, 0.f, 0.f};

    // LDS[row][b] = global blk (b ^ (row&7)); readers apply the same XOR.
    // K-tail A-blocks load 16B of zeros from zp (global scratch) so every
    // wave issues exactly LW VMEM ops per STAGE. OOB M-rows read adjacent
    // mapped workspace (finite bf16; those acc rows are never stored).
    auto STAGE = [&](int cc, int slot) {
        unsigned short* Abuf = arena + slot * SLOT;
        unsigned short* Bbuf = Abuf + ASH;
        const int k0 = kbase + cc * COLS;
#pragma unroll
        for (int i = 0; i < AUNITS / 256; ++i) {
            const int u    = tid + i * 256;
            const int row  = u >> 3;
            const int gblk = (u & 7) ^ (row & 7);
            const int k    = k0 + gblk * 8;
            const unsigned short* g = (k + 8 <= Kd)
                ? A + (size_t)(m0 + row) * Kd + k
                : zp + (u & 3) * 8;
            __builtin_amdgcn_global_load_lds(
                (const __attribute__((address_space(1))) void*)g,
                (__attribute__((address_space(3))) void*)(Abuf + u * 8),
                16, 0, 0);
        }
#pragma unroll
        for (int i = 0; i < BUNITS / 256; ++i) {
            const int u    = tid + i * 256;
            const int row  = u >> 3;
            const int gblk = (u & 7) ^ (row & 7);
            const unsigned short* g = Bp + (size_t)row * Kd + k0 + gblk * 8;
            __builtin_amdgcn_global_load_lds(
                (const __attribute__((address_space(1))) void*)g,
                (__attribute__((address_space(3))) void*)(Bbuf + u * 8),
                16, 0, 0);
        }
    };

    STAGE(0, 0);
    STAGE(1, 1);

    for (int cc = 0; cc < ccmax; ++cc) {
        asm volatile("" ::: "memory");
        __builtin_amdgcn_s_barrier();            // #1: MFMA(cc-1) reads done
        if (cc + 2 < ccmax) STAGE(cc + 2, (cc + 2) % 3);
        const int ahead = min(2, ccmax - 1 - cc);
        if      (ahead == 2) vwait<2 * LW>();    // tile cc landed; cc+1,cc+2 in flight
        else if (ahead == 1) vwait<LW>();
        else                 vwait<0>();
        __builtin_amdgcn_s_barrier();            // #2: everyone's tile cc landed
        asm volatile("" ::: "memory");

        const unsigned short* Ac = arena + (cc % 3) * SLOT;
        const unsigned short* Bc = Ac + ASH;
#pragma unroll
        for (int s = 0; s < 2; ++s) {
            bf16x8 av[RF];
#pragma unroll
            for (int t = 0; t < RF; ++t) {
                const int row = (wave * RF + t) * 16 + l16;
                av[t] = *(const bf16x8*)
                    &Ac[row * COLS + (((s * 4 + quad) ^ (l16 & 7)) * 8)];
            }
#pragma unroll
            for (int f = 0; f < NFRAG; ++f) {
                bf16x8 bv = *(const bf16x8*)
                    &Bc[(f * 16 + l16) * COLS + (((s * 4 + quad) ^ (l16 & 7)) * 8)];
#pragma unroll
                for (int t = 0; t < RF; ++t)
                    acc[t][f] = __builtin_amdgcn_mfma_f32_16x16x32_bf16(
                        av[t], bv, acc[t][f], 0, 0, 0);
            }
        }
    }

    // epilogue: 3 chunked transpose passes of 64 rows through the arena
    unsigned short* Cs = arena;   // [64][CSP]
    unsigned short* Pc = P + ((size_t)chunk * M + m0) * NTF + zhalf * NT;
#pragma unroll
    for (int p = 0; p < 3; ++p) {
        __syncthreads();
#pragma unroll
        for (int t = 0; t < RF; ++t) {
            const int fr = wave * RF + t;
            if ((fr >> 2) == p) {
                const int rb = (fr & 3) * 16 + quad * 4;
#pragma unroll
                for (int f = 0; f < NFRAG; ++f) {
                    const int col = f * 16 + l16;
#pragma unroll
                    for (int r = 0; r < 4; ++r)
                        Cs[(rb + r) * CSP + col] = f2bf(acc[t][f][r]);
                }
            }
        }
        __syncthreads();
        constexpr int UNITS = 64 * NT / 8;
        for (int u = tid; u < UNITS; u += 256) {
            const int row = (u * 8) / NT, col = (u * 8) % NT;
            if (m0 + p * 64 + row < M)
                *(uint4*)&Pc[(size_t)(p * 64 + row) * NTF + col] =
                    *(const uint4*)&Cs[row * CSP + col];
        }
    }
}

// Merged GEMM: blockIdx.y < CH2_ -> h-chunk; else x-(chunk,half).
__global__ __launch_bounds__(256) void gemm_all_kernel(
    const unsigned short* __restrict__ Tx, const unsigned short* __restrict__ B1t,
    unsigned short* __restrict__ P1,
    const unsigned short* __restrict__ Th, const unsigned short* __restrict__ B2t,
    unsigned short* __restrict__ P2, const unsigned short* __restrict__ zp)
{
    // 3 slots x (A 24576B + B 16384B) = 122880 B -> 1 block/CU
    __shared__ __align__(16) unsigned short arena[3 * 20480];
    const int y = blockIdx.y;
    if (y < CH2_) {
        gemm_body<128, 128, CPB_, 10>(arena, Th, B2t, zp, P2, NN_, KK_ * CHID_, y, 0);
    } else {
        const int g = y - CH2_;            // 0..7 -> (chunk 0..3, half 0..1)
        gemm_body<96, 192, CPB_, 9>(arena, Tx, B1t, zp, P1, NN_, KK_ * CIN_, g >> 1, g & 1);
    }
}

// ---------------------------------------------------------------------------
// Epilogue: one wave per node, lane = output channel. Sums bf16 split-K
// partials (L2-resident), mean-agg, root GEMV, GRU gates.
// ---------------------------------------------------------------------------
__global__ __launch_bounds__(256) void epilogue_kernel(
    const unsigned short* __restrict__ P1, const unsigned short* __restrict__ P2,
    const int* __restrict__ offs,
    const float* __restrict__ x, const float* __restrict__ hidden,
    const float* __restrict__ root_xr, const float* __restrict__ root_hr,
    const float* __restrict__ root_xz, const float* __restrict__ root_hz,
    const float* __restrict__ root_xn,
    const float* __restrict__ b_xr, const float* __restrict__ b_hr,
    const float* __restrict__ b_xz, const float* __restrict__ b_hz,
    const float* __restrict__ b_xn,
    float* __restrict__ out)
{
    __shared__ float xsh[4][32];
    __shared__ float hsh[4][64];
    const int w = threadIdx.x >> 6;
    const int o = threadIdx.x & 63;
    const int m = blockIdx.x * 4 + w;
    if (m >= NN_) return;

    if (o < 32) xsh[w][o] = x[(size_t)m * 32 + o];
    const float hval = hidden[(size_t)m * 64 + o];
    hsh[w][o] = hval;

    float axr = 0.f, axz = 0.f, axn = 0.f;
#pragma unroll
    for (int c = 0; c < CH1_; ++c) {
        const unsigned short* p = P1 + ((size_t)c * NN_ + m) * 192;
        axr += bf2f(p[o]); axz += bf2f(p[64 + o]); axn += bf2f(p[128 + o]);
    }
    float ahr = 0.f, ahz = 0.f;
#pragma unroll
    for (int c = 0; c < CH2_; ++c) {
        const unsigned short* p = P2 + ((size_t)c * NN_ + m) * 128;
        ahr += bf2f(p[o]); ahz += bf2f(p[64 + o]);
    }

    const int   dg   = offs[m + 1] - offs[m];
    const float dinv = 1.0f / fmaxf((float)dg, 1.0f);
    axr *= dinv; axz *= dinv; axn *= dinv; ahr *= dinv; ahz *= dinv;

    float sxr = 0.f, sxz = 0.f, sxn = 0.f;
#pragma unroll
    for (int c = 0; c < CIN_; ++c) {
        float xv = xsh[w][c];
        sxr += xv * root_xr[c * 64 + o];
        sxz += xv * root_xz[c * 64 + o];
        sxn += xv * root_xn[c * 64 + o];
    }
    float shr = 0.f, shz = 0.f;
#pragma unroll
    for (int c = 0; c < CHID_; ++c) {
        float hv = hsh[w][c];
        shr += hv * root_hr[c * 64 + o];
        shz += hv * root_hz[c * 64 + o];
    }

    const float conv_xr = axr + sxr + b_xr[o];
    const float conv_xz = axz + sxz + b_xz[o];
    const float conv_xn = axn + sxn + b_xn[o];
    const float hr_out  = ahr + shr + b_hr[o];
    const float conv_hz = ahz + shz + b_hz[o];

    const float rg = 1.0f / (1.0f + expf(-(conv_xr + hr_out)));
    const float zg = 1.0f / (1.0f + expf(-(conv_xz + conv_hz)));
    const float ng = tanhf(conv_xn + rg * hr_out);
    out[(size_t)m * 64 + o] = (1.0f - zg) * ng + zg * hval;
}

// ---------------------------------------------------------------------------
extern "C" void kernel_launch(void* const* d_in, const int* in_sizes, int n_in,
                              void* d_out, int out_size, void* d_ws, size_t ws_size,
                              hipStream_t stream)
{
    const float* x       = (const float*)d_in[0];
    const float* hidden  = (const float*)d_in[1];
    const int*   ei      = (const int*)  d_in[2];
    const float* attr    = (const float*)d_in[3];
    const float* W_xr    = (const float*)d_in[4];
    const float* root_xr = (const float*)d_in[5];
    const float* b_xr    = (const float*)d_in[6];
    const float* W_hr    = (const float*)d_in[7];
    const float* root_hr = (const float*)d_in[8];
    const float* b_hr    = (const float*)d_in[9];
    const float* W_xz    = (const float*)d_in[10];
    const float* root_xz = (const float*)d_in[11];
    const float* b_xz    = (const float*)d_in[12];
    const float* W_hz    = (const float*)d_in[13];
    const float* root_hz = (const float*)d_in[14];
    const float* b_hz    = (const float*)d_in[15];
    const float* W_xn    = (const float*)d_in[16];
    const float* root_xn = (const float*)d_in[17];
    const float* b_xn    = (const float*)d_in[18];
    // d_in[19..21] (W_hn/root_hn/b_hn) are dead: reference reuses hr_out.
    float* out = (float*)d_out;

    // Workspace (~175 MB). No aliasing (gemm-x reads Tx while gemm-h writes
    // P2 concurrently inside gemm_all). A/B staging may read a few rows past
    // a region's end -- all land in adjacent mapped workspace (finite bf16);
    // A K-tail loads zeros from zpad so those products are exactly 0.
    char* w = (char*)d_ws;
    unsigned short* Tx  = (unsigned short*)w; w += (size_t)NN_ * KK_ * CIN_  * 2;  // 48 MB
    unsigned short* Th  = (unsigned short*)w; w += (size_t)NN_ * KK_ * CHID_ * 2;  // 96 MB
    unsigned short* B1t = (unsigned short*)w; w += (size_t)192 * KK_ * CIN_  * 2;  // 1.5 MB
    unsigned short* B2t = (unsigned short*)w; w += (size_t)128 * KK_ * CHID_ * 2;  // 2.0 MB
    unsigned short* P1  = (unsigned short*)w; w += (size_t)CH1_ * NN_ * 192 * 2;   // 9.2 MB
    unsigned short* P2  = (unsigned short*)w; w += (size_t)CH2_ * NN_ * 128 * 2;   // 12.3 MB
    float4* meta_s = (float4*)w; w += (size_t)EE_ * 16;                            // 3.07 MB
    int* src_s  = (int*)w;   w += (size_t)EE_ * 4;                                 // 0.77 MB
    int* deg    = (int*)w;   w += (size_t)NN_ * 4;
    int* offs   = (int*)w;   w += (size_t)(NN_ + 4) * 4;
    int* cursor = (int*)w;   w += (size_t)NN_ * 4;
    unsigned short* zpad = (unsigned short*)w; w += 256;                           // zeroed

    const int MT = (NN_ + MTILE_ - 1) / MTILE_;   // 32 m-tiles

    hipMemsetAsync(deg, 0, (size_t)NN_ * 4, stream);
    hipMemsetAsync(zpad, 0, 256, stream);

    // ---- launch 1: deg count + weight packs (independent, merged) ----
    const int PACKB = (PK1_ + PK2_ + 255) / 256;
    count_pack_kernel<<<CB_ + PACKB, 256, 0, stream>>>(
        ei, deg, W_xr, W_xz, W_xn, W_hr, W_hz, B1t, B2t);

    // ---- scan + sorted edge records ----
    scan_kernel<<<1, 1024, 0, stream>>>(deg, offs, cursor);
    prep_kernel<<<(EE_ + 255) / 256, 256, 0, stream>>>(ei, attr, cursor, meta_s, src_s);

    // ---- T builds: MFMA formulation ----
    build_T_kernel<CHID_><<<NN_, 256, 0, stream>>>(meta_s, src_s, hidden, offs, Th);
    build_T_kernel<CIN_><<<NN_, 256, 0, stream>>>(meta_s, src_s, x, offs, Tx);

    // ---- merged x+h GEMMs (co-resident, one launch) ----
    gemm_all_kernel<<<dim3(MT, CH2_ + 2 * CH1_), 256, 0, stream>>>(
        Tx, B1t, P1, Th, B2t, P2, zpad);

    // ---- fused reduce + GRU epilogue (wave per node) ----
    epilogue_kernel<<<(NN_ + 3) / 4, 256, 0, stream>>>(
        P1, P2, offs, x, hidden,
        root_xr, root_hr, root_xz, root_hz, root_xn,
        b_xr, b_hr, b_xz, b_hz, b_xn, out);
}